// Round 1
// baseline (1076.731 us; speedup 1.0000x reference)
//
#include <hip/hip_runtime.h>
#include <math.h>

#define NE 5
#define NK 3
#define NC 10

// One block per image. 256 threads = 4 waves.
// LDS: img 784 + w1 288 + b1 32 + pool1 5408 + f 1600 + red 64 + gate 8 ~= 32.7 KB -> 4 blocks/CU.
__launch_bounds__(256, 4)
__global__ void moe_fused(const float* __restrict__ x,
                          const float* __restrict__ w1, const float* __restrict__ b1,
                          const float* __restrict__ w2, const float* __restrict__ b2,
                          const float* __restrict__ gw, const float* __restrict__ gb,
                          const float* __restrict__ ew, const float* __restrict__ eb,
                          float* __restrict__ out)
{
    __shared__ float s_img[784];    // [28][28]
    __shared__ float s_w1[288];     // [3][3][32]
    __shared__ float s_b1[32];
    __shared__ float s_p1[5408];    // [13][13][32]
    __shared__ float s_f[1600];     // [5][5][64] == flatten order
    __shared__ float s_red[64];
    __shared__ float s_gate[8];

    const int t = threadIdx.x;
    const int b = blockIdx.x;
    const int lane = t & 63;
    const int wv = t >> 6;

    // ---- Phase A: stage image + conv1 weights ----
    for (int i = t; i < 784; i += 256) s_img[i] = x[b * 784 + i];
    for (int i = t; i < 288; i += 256) s_w1[i] = w1[i];
    if (t < 32) s_b1[t] = b1[t];
    __syncthreads();

    // ---- Phase B: conv1 + relu + maxpool2 -> s_p1[13][13][32] ----
    {
        const int co = t & 31;                 // constant per thread across o-loop
        float w1r[9];
        #pragma unroll
        for (int k = 0; k < 9; k++) w1r[k] = s_w1[k * 32 + co];
        const float b1r = s_b1[co];
        for (int o = t; o < 5408; o += 256) {
            const int pos = o >> 5;
            const int py = pos / 13, px = pos % 13;
            float m = -1e30f;
            #pragma unroll
            for (int dy = 0; dy < 2; dy++)
            #pragma unroll
            for (int dx = 0; dx < 2; dx++) {
                const int iy = 2 * py + dy, ix = 2 * px + dx;
                float s = b1r;
                #pragma unroll
                for (int ky = 0; ky < 3; ky++)
                #pragma unroll
                for (int kx = 0; kx < 3; kx++)
                    s = fmaf(s_img[(iy + ky) * 28 + (ix + kx)], w1r[ky * 3 + kx], s);
                m = fmaxf(m, s);
            }
            s_p1[o] = fmaxf(m, 0.f);           // relu(max) == max(relu) (monotone)
        }
    }
    __syncthreads();

    // ---- Phase C: conv2 + relu + maxpool2 -> s_f[5][5][64] ----
    {
        const int co = t & 63;                 // output channel = lane
        const int g  = t >> 6;                 // wave id 0..3
        float acc[7][4];
        int   base[7];
        #pragma unroll
        for (int i = 0; i < 7; i++) {
            const int p = g + 4 * i;           // pooled position 0..27 (>=25 is dummy)
            const int py = p / 5, px = p % 5;
            base[i] = (p < 25) ? ((2 * py * 13 + 2 * px) * 32) : 0;
            #pragma unroll
            for (int w = 0; w < 4; w++) acc[i][w] = 0.f;
        }
        #pragma unroll
        for (int ky = 0; ky < 3; ky++)
        #pragma unroll
        for (int kx = 0; kx < 3; kx++) {
            const int koff = (ky * 13 + kx) * 32;
            const float* wp = w2 + ((ky * 3 + kx) * 32) * 64 + co;
            #pragma unroll 2
            for (int ci = 0; ci < 32; ci++) {
                const float w = wp[ci * 64];
                #pragma unroll
                for (int i = 0; i < 7; i++) {
                    const int a = base[i] + koff + ci;
                    acc[i][0] = fmaf(s_p1[a],        w, acc[i][0]);  // (dy,dx)=(0,0)
                    acc[i][1] = fmaf(s_p1[a +  32],  w, acc[i][1]);  // (0,1)
                    acc[i][2] = fmaf(s_p1[a + 416],  w, acc[i][2]);  // (1,0)
                    acc[i][3] = fmaf(s_p1[a + 448],  w, acc[i][3]);  // (1,1)
                }
            }
        }
        const float b2r = b2[co];
        #pragma unroll
        for (int i = 0; i < 7; i++) {
            const int p = g + 4 * i;
            if (p < 25) {
                float m = fmaxf(fmaxf(acc[i][0], acc[i][1]), fmaxf(acc[i][2], acc[i][3]));
                s_f[p * 64 + co] = fmaxf(m + b2r, 0.f);
            }
        }
    }
    __syncthreads();

    // ---- Phase D: gate logits (f @ gw + gb) ----
    {
        float gl[NE] = {0.f, 0.f, 0.f, 0.f, 0.f};
        for (int d = t; d < 1600; d += 256) {
            const float fd = s_f[d];
            #pragma unroll
            for (int e = 0; e < NE; e++) gl[e] = fmaf(fd, gw[d * NE + e], gl[e]);
        }
        #pragma unroll
        for (int e = 0; e < NE; e++) {
            #pragma unroll
            for (int off = 32; off; off >>= 1) gl[e] += __shfl_down(gl[e], off, 64);
        }
        if (lane == 0) {
            #pragma unroll
            for (int e = 0; e < NE; e++) s_red[wv * NE + e] = gl[e];
        }
    }
    __syncthreads();
    if (t == 0) {
        #pragma unroll
        for (int e = 0; e < NE; e++)
            s_gate[e] = s_red[e] + s_red[NE + e] + s_red[2 * NE + e] + s_red[3 * NE + e] + gb[e];
    }
    __syncthreads();

    // ---- Phase E: softmax over 5 + stable top-3 (every thread, uniform) ----
    int   idxk[NK];
    float wk[NK];
    {
        float gv[NE], pe[NE];
        #pragma unroll
        for (int e = 0; e < NE; e++) gv[e] = s_gate[e];
        float mg = gv[0];
        #pragma unroll
        for (int e = 1; e < NE; e++) mg = fmaxf(mg, gv[e]);
        float se = 0.f;
        #pragma unroll
        for (int e = 0; e < NE; e++) { pe[e] = expf(gv[e] - mg); se += pe[e]; }
        const float inv = 1.f / se;
        #pragma unroll
        for (int e = 0; e < NE; e++) pe[e] *= inv;
        bool used[NE] = {false, false, false, false, false};
        #pragma unroll
        for (int k = 0; k < NK; k++) {
            int bi = 0; float bv = -1e30f;
            #pragma unroll
            for (int e = 0; e < NE; e++)
                if (!used[e] && pe[e] > bv) { bv = pe[e]; bi = e; }   // strict > : lowest index wins ties
            used[bi] = true; idxk[k] = bi; wk[k] = bv;
        }
    }

    // ---- Phase F: top-3 expert GEMVs, weighted sum, softmax(10) ----
    {
        float a10[NC];
        #pragma unroll
        for (int h = 0; h < NC; h++) a10[h] = 0.f;
        for (int d = t; d < 1600; d += 256) {
            const float fd = s_f[d];
            #pragma unroll
            for (int k = 0; k < NK; k++) {
                const float* ep = ew + (idxk[k] * 1600 + d) * NC;
                const float wf = wk[k] * fd;
                #pragma unroll
                for (int h = 0; h < NC; h++) a10[h] = fmaf(wf, ep[h], a10[h]);
            }
        }
        #pragma unroll
        for (int h = 0; h < NC; h++) {
            #pragma unroll
            for (int off = 32; off; off >>= 1) a10[h] += __shfl_down(a10[h], off, 64);
        }
        if (lane == 0) {
            #pragma unroll
            for (int h = 0; h < NC; h++) s_red[wv * NC + h] = a10[h];
        }
        __syncthreads();
        if (t == 0) {
            float c10[NC];
            #pragma unroll
            for (int h = 0; h < NC; h++)
                c10[h] = s_red[h] + s_red[NC + h] + s_red[2 * NC + h] + s_red[3 * NC + h];
            #pragma unroll
            for (int k = 0; k < NK; k++)
                #pragma unroll
                for (int h = 0; h < NC; h++)
                    c10[h] = fmaf(wk[k], eb[idxk[k] * NC + h], c10[h]);
            float mx = c10[0];
            #pragma unroll
            for (int h = 1; h < NC; h++) mx = fmaxf(mx, c10[h]);
            float se = 0.f;
            #pragma unroll
            for (int h = 0; h < NC; h++) { c10[h] = expf(c10[h] - mx); se += c10[h]; }
            const float inv = 1.f / se;
            #pragma unroll
            for (int h = 0; h < NC; h++) out[b * NC + h] = c10[h] * inv;
        }
    }
}

extern "C" void kernel_launch(void* const* d_in, const int* in_sizes, int n_in,
                              void* d_out, int out_size, void* d_ws, size_t ws_size,
                              hipStream_t stream) {
    const float* x   = (const float*)d_in[0];
    const float* w1  = (const float*)d_in[1];
    const float* b1  = (const float*)d_in[2];
    const float* w2  = (const float*)d_in[3];
    const float* b2  = (const float*)d_in[4];
    const float* gw  = (const float*)d_in[5];
    const float* gb  = (const float*)d_in[6];
    const float* ew  = (const float*)d_in[7];
    const float* eb  = (const float*)d_in[8];
    float* out = (float*)d_out;

    const int batch = in_sizes[0] / 784;   // 8192
    moe_fused<<<batch, 256, 0, stream>>>(x, w1, b1, w2, b2, gw, gb, ew, eb, out);
}

// Round 4
// 1072.081 us; speedup vs baseline: 1.0043x; 1.0043x over previous
//
#include <hip/hip_runtime.h>
#include <math.h>

#define NE 5
#define NK 3
#define NC 10
#define NT 320   // 5 waves: one wave per pooled output row in conv2

// One block per image.
// LDS: img 784 + w1 288 + b1 32 + p1 5408 + f 1600 + red 64 + gate 8 = 8184 f ~= 32.7 KB -> 4 blocks/CU.
__launch_bounds__(NT, 5)
__global__ void moe_fused(const float* __restrict__ x,
                          const float* __restrict__ w1, const float* __restrict__ b1,
                          const float* __restrict__ w2, const float* __restrict__ b2,
                          const float* __restrict__ gw, const float* __restrict__ gb,
                          const float* __restrict__ ew, const float* __restrict__ eb,
                          float* __restrict__ out)
{
    __shared__ float s_img[784];    // [28][28]
    __shared__ float s_w1[288];     // [3][3][32]
    __shared__ float s_b1[32];
    __shared__ float s_p1[5408];    // [ci=32][169]  channel-major: conv2 reads are wave-broadcast
    __shared__ float s_f[1600];     // [5][5][64] == flatten order
    __shared__ float s_red[64];
    __shared__ float s_gate[8];

    const int t = threadIdx.x;
    const int b = blockIdx.x;
    const int lane = t & 63;
    const int wv = t >> 6;          // 0..4

    // ---- Phase A: stage image + conv1 weights ----
    for (int i = t; i < 784; i += NT) s_img[i] = x[b * 784 + i];
    for (int i = t; i < 288; i += NT) s_w1[i] = w1[i];
    if (t < 32) s_b1[t] = b1[t];
    __syncthreads();

    // ---- Phase B: conv1 + relu + maxpool2 -> s_p1[co][13*13] ----
    {
        const int co = t & 31;
        float w1r[9];
        #pragma unroll
        for (int k = 0; k < 9; k++) w1r[k] = s_w1[k * 32 + co];
        const float b1r = s_b1[co];
        for (int o = t; o < 5408; o += NT) {
            const int pos = o >> 5;            // (o&31)==co since NT%32==0
            const int py = pos / 13, px = pos % 13;
            // register-cache the 4x4 pixel patch (wave-broadcast LDS reads)
            float p[4][4];
            #pragma unroll
            for (int dy = 0; dy < 4; dy++)
            #pragma unroll
            for (int dx = 0; dx < 4; dx++)
                p[dy][dx] = s_img[(2 * py + dy) * 28 + (2 * px + dx)];
            float m = -1e30f;
            #pragma unroll
            for (int dy = 0; dy < 2; dy++)
            #pragma unroll
            for (int dx = 0; dx < 2; dx++) {
                float s = b1r;
                #pragma unroll
                for (int ky = 0; ky < 3; ky++)
                #pragma unroll
                for (int kx = 0; kx < 3; kx++)
                    s = fmaf(p[dy + ky][dx + kx], w1r[ky * 3 + kx], s);
                m = fmaxf(m, s);
            }
            s_p1[co * 169 + pos] = fmaxf(m, 0.f);   // relu(max)==max(relu)
        }
    }
    __syncthreads();

    // ---- Phase C: conv2 + relu + maxpool2 -> s_f[5][5][64] ----
    // wave wv owns pooled row pr=wv; thread owns output channel co=lane.
    // Register sliding window: 12-col input row reused across 3 kx and 2 conv rows.
    {
        const int co = lane;
        const int pr = wv;                       // pooled row 0..4
        const float* __restrict__ wp = w2 + co;  // w2[((ky*3+kx)*32+ci)*64 + co]
        float acc[2][10];
        #pragma unroll
        for (int cy = 0; cy < 2; cy++)
            #pragma unroll
            for (int px = 0; px < 10; px++) acc[cy][px] = 0.f;

        float w[9], wn[9];
        #pragma unroll
        for (int k = 0; k < 9; k++) w[k] = wp[(k * 32) * 64];
        const int pbase0 = 2 * pr * 13;

        #pragma unroll 1
        for (int ci = 0; ci < 32; ci++) {
            if (ci < 31) {                       // prefetch next ci's 9 weights
                #pragma unroll
                for (int k = 0; k < 9; k++) wn[k] = wp[(k * 32 + ci + 1) * 64];
            }
            const int pb = ci * 169 + pbase0;
            #pragma unroll
            for (int r = 0; r < 4; r++) {        // input rows 2pr..2pr+3
                float in[12];
                #pragma unroll
                for (int xx = 0; xx < 12; xx++) in[xx] = s_p1[pb + r * 13 + xx];
                #pragma unroll
                for (int cy = 0; cy < 2; cy++) {
                    const int ky = r - cy;       // compile-time after unroll
                    if (0 <= ky && ky < 3) {
                        #pragma unroll
                        for (int kx = 0; kx < 3; kx++) {
                            const float wv_ = w[ky * 3 + kx];
                            #pragma unroll
                            for (int px = 0; px < 10; px++)
                                acc[cy][px] = fmaf(in[px + kx], wv_, acc[cy][px]);
                        }
                    }
                }
            }
            if (ci < 31) {
                #pragma unroll
                for (int k = 0; k < 9; k++) w[k] = wn[k];
            }
        }
        const float b2r = b2[co];
        #pragma unroll
        for (int pxp = 0; pxp < 5; pxp++) {
            float m = fmaxf(fmaxf(acc[0][2 * pxp], acc[0][2 * pxp + 1]),
                            fmaxf(acc[1][2 * pxp], acc[1][2 * pxp + 1]));
            s_f[(pr * 5 + pxp) * 64 + co] = fmaxf(m + b2r, 0.f);
        }
    }
    __syncthreads();

    // ---- Phase D: gate logits (f @ gw + gb) ----
    {
        float gl[NE] = {0.f, 0.f, 0.f, 0.f, 0.f};
        for (int d = t; d < 1600; d += NT) {
            const float fd = s_f[d];
            #pragma unroll
            for (int e = 0; e < NE; e++) gl[e] = fmaf(fd, gw[d * NE + e], gl[e]);
        }
        #pragma unroll
        for (int e = 0; e < NE; e++) {
            #pragma unroll
            for (int off = 32; off; off >>= 1) gl[e] += __shfl_down(gl[e], off, 64);
        }
        if (lane == 0) {
            #pragma unroll
            for (int e = 0; e < NE; e++) s_red[wv * NE + e] = gl[e];
        }
    }
    __syncthreads();
    if (t == 0) {
        #pragma unroll
        for (int e = 0; e < NE; e++) {
            float s = gb[e];
            #pragma unroll
            for (int w_ = 0; w_ < 5; w_++) s += s_red[w_ * NE + e];
            s_gate[e] = s;
        }
    }
    __syncthreads();

    // ---- Phase E: softmax over 5 + stable top-3 (uniform per thread) ----
    int   idxk[NK];
    float wk[NK];
    {
        float gv[NE], pe[NE];
        #pragma unroll
        for (int e = 0; e < NE; e++) gv[e] = s_gate[e];
        float mg = gv[0];
        #pragma unroll
        for (int e = 1; e < NE; e++) mg = fmaxf(mg, gv[e]);
        float se = 0.f;
        #pragma unroll
        for (int e = 0; e < NE; e++) { pe[e] = expf(gv[e] - mg); se += pe[e]; }
        const float inv = 1.f / se;
        #pragma unroll
        for (int e = 0; e < NE; e++) pe[e] *= inv;
        bool used[NE] = {false, false, false, false, false};
        #pragma unroll
        for (int k = 0; k < NK; k++) {
            int bi = 0; float bv = -1e30f;
            #pragma unroll
            for (int e = 0; e < NE; e++)
                if (!used[e] && pe[e] > bv) { bv = pe[e]; bi = e; }  // strict >: lowest idx wins ties
            used[bi] = true; idxk[k] = bi; wk[k] = bv;
        }
    }

    // ---- Phase F: top-3 expert GEMVs, weighted sum, softmax(10) ----
    {
        float a10[NC];
        #pragma unroll
        for (int h = 0; h < NC; h++) a10[h] = 0.f;
        for (int d = t; d < 1600; d += NT) {
            const float fd = s_f[d];
            #pragma unroll
            for (int k = 0; k < NK; k++) {
                const float* ep = ew + (idxk[k] * 1600 + d) * NC;
                const float wf = wk[k] * fd;
                #pragma unroll
                for (int h = 0; h < NC; h++) a10[h] = fmaf(wf, ep[h], a10[h]);
            }
        }
        #pragma unroll
        for (int h = 0; h < NC; h++) {
            #pragma unroll
            for (int off = 32; off; off >>= 1) a10[h] += __shfl_down(a10[h], off, 64);
        }
        if (lane == 0) {
            #pragma unroll
            for (int h = 0; h < NC; h++) s_red[wv * NC + h] = a10[h];
        }
        __syncthreads();
        if (t == 0) {
            float c10[NC];
            #pragma unroll
            for (int h = 0; h < NC; h++) {
                float s = 0.f;
                #pragma unroll
                for (int w_ = 0; w_ < 5; w_++) s += s_red[w_ * NC + h];
                c10[h] = s;
            }
            #pragma unroll
            for (int k = 0; k < NK; k++)
                #pragma unroll
                for (int h = 0; h < NC; h++)
                    c10[h] = fmaf(wk[k], eb[idxk[k] * NC + h], c10[h]);
            float mx = c10[0];
            #pragma unroll
            for (int h = 1; h < NC; h++) mx = fmaxf(mx, c10[h]);
            float se = 0.f;
            #pragma unroll
            for (int h = 0; h < NC; h++) { c10[h] = expf(c10[h] - mx); se += c10[h]; }
            const float inv = 1.f / se;
            #pragma unroll
            for (int h = 0; h < NC; h++) out[b * NC + h] = c10[h] * inv;
        }
    }
}

extern "C" void kernel_launch(void* const* d_in, const int* in_sizes, int n_in,
                              void* d_out, int out_size, void* d_ws, size_t ws_size,
                              hipStream_t stream) {
    const float* x   = (const float*)d_in[0];
    const float* w1  = (const float*)d_in[1];
    const float* b1  = (const float*)d_in[2];
    const float* w2  = (const float*)d_in[3];
    const float* b2  = (const float*)d_in[4];
    const float* gw  = (const float*)d_in[5];
    const float* gb  = (const float*)d_in[6];
    const float* ew  = (const float*)d_in[7];
    const float* eb  = (const float*)d_in[8];
    float* out = (float*)d_out;

    const int batch = in_sizes[0] / 784;   // 8192
    moe_fused<<<batch, NT, 0, stream>>>(x, w1, b1, w2, b2, gw, gb, ew, eb, out);
}

// Round 5
// 868.288 us; speedup vs baseline: 1.2401x; 1.2347x over previous
//
#include <hip/hip_runtime.h>
#include <math.h>

#define NE 5
#define NK 3
#define NC 10
#define NT 320   // 5 waves: one wave per pooled output row in conv2

// One block per image.
// LDS: img 784 + w1 288 + b1 32 + p1 5408 + f 1600 + red 64 + gate 8 = 8184 f ~= 32.7 KB -> 4 blocks/CU.
// __launch_bounds__(NT, 4): VGPR cap 128. Do NOT use min-waves=5 — a toolchain
// compiled that to 48 VGPRs and spilled ~130 MB to scratch (R4 post-mortem).
__launch_bounds__(NT, 4)
__global__ void moe_fused(const float* __restrict__ x,
                          const float* __restrict__ w1, const float* __restrict__ b1,
                          const float* __restrict__ w2, const float* __restrict__ b2,
                          const float* __restrict__ gw, const float* __restrict__ gb,
                          const float* __restrict__ ew, const float* __restrict__ eb,
                          float* __restrict__ out)
{
    __shared__ float s_img[784];    // [28][28]
    __shared__ float s_w1[288];     // [3][3][32]
    __shared__ float s_b1[32];
    __shared__ float s_p1[5408];    // [ci=32][169]  channel-major: conv2 reads are wave-broadcast
    __shared__ float s_f[1600];     // [5][5][64] == flatten order
    __shared__ float s_red[64];
    __shared__ float s_gate[8];

    const int t = threadIdx.x;
    const int b = blockIdx.x;
    const int lane = t & 63;
    const int wv = t >> 6;          // 0..4

    // ---- Phase A: stage image + conv1 weights ----
    for (int i = t; i < 784; i += NT) s_img[i] = x[b * 784 + i];
    for (int i = t; i < 288; i += NT) s_w1[i] = w1[i];
    if (t < 32) s_b1[t] = b1[t];
    __syncthreads();

    // ---- Phase B: conv1 + relu + maxpool2 -> s_p1[co][13*13] ----
    {
        const int co = t & 31;
        float w1r[9];
        #pragma unroll
        for (int k = 0; k < 9; k++) w1r[k] = s_w1[k * 32 + co];
        const float b1r = s_b1[co];
        for (int o = t; o < 5408; o += NT) {
            const int pos = o >> 5;            // (o&31)==co since NT%32==0
            const int py = pos / 13, px = pos % 13;
            // register-cache the 4x4 pixel patch (wave-broadcast LDS reads)
            float p[4][4];
            #pragma unroll
            for (int dy = 0; dy < 4; dy++)
            #pragma unroll
            for (int dx = 0; dx < 4; dx++)
                p[dy][dx] = s_img[(2 * py + dy) * 28 + (2 * px + dx)];
            float m = -1e30f;
            #pragma unroll
            for (int dy = 0; dy < 2; dy++)
            #pragma unroll
            for (int dx = 0; dx < 2; dx++) {
                float s = b1r;
                #pragma unroll
                for (int ky = 0; ky < 3; ky++)
                #pragma unroll
                for (int kx = 0; kx < 3; kx++)
                    s = fmaf(p[dy + ky][dx + kx], w1r[ky * 3 + kx], s);
                m = fmaxf(m, s);
            }
            s_p1[co * 169 + pos] = fmaxf(m, 0.f);   // relu(max)==max(relu)
        }
    }
    __syncthreads();

    // ---- Phase C: conv2 + relu + maxpool2 -> s_f[5][5][64] ----
    // wave wv owns pooled row pr=wv; thread owns output channel co=lane.
    // Register sliding window: 12-col input row reused across 3 kx and 2 conv rows.
    {
        const int co = lane;
        const int pr = wv;                       // pooled row 0..4
        const float* __restrict__ wp = w2 + co;  // w2[((ky*3+kx)*32+ci)*64 + co]
        float acc[2][10];
        #pragma unroll
        for (int cy = 0; cy < 2; cy++)
            #pragma unroll
            for (int px = 0; px < 10; px++) acc[cy][px] = 0.f;

        float w[9], wn[9];
        #pragma unroll
        for (int k = 0; k < 9; k++) w[k] = wp[(k * 32) * 64];
        const int pbase0 = 2 * pr * 13;

        #pragma unroll 1
        for (int ci = 0; ci < 32; ci++) {
            if (ci < 31) {                       // prefetch next ci's 9 weights
                #pragma unroll
                for (int k = 0; k < 9; k++) wn[k] = wp[(k * 32 + ci + 1) * 64];
            }
            const int pb = ci * 169 + pbase0;
            #pragma unroll
            for (int r = 0; r < 4; r++) {        // input rows 2pr..2pr+3
                float in[12];
                #pragma unroll
                for (int xx = 0; xx < 12; xx++) in[xx] = s_p1[pb + r * 13 + xx];
                #pragma unroll
                for (int cy = 0; cy < 2; cy++) {
                    const int ky = r - cy;       // compile-time after unroll
                    if (0 <= ky && ky < 3) {
                        #pragma unroll
                        for (int kx = 0; kx < 3; kx++) {
                            const float wv_ = w[ky * 3 + kx];
                            #pragma unroll
                            for (int px = 0; px < 10; px++)
                                acc[cy][px] = fmaf(in[px + kx], wv_, acc[cy][px]);
                        }
                    }
                }
            }
            if (ci < 31) {
                #pragma unroll
                for (int k = 0; k < 9; k++) w[k] = wn[k];
            }
        }
        const float b2r = b2[co];
        #pragma unroll
        for (int pxp = 0; pxp < 5; pxp++) {
            float m = fmaxf(fmaxf(acc[0][2 * pxp], acc[0][2 * pxp + 1]),
                            fmaxf(acc[1][2 * pxp], acc[1][2 * pxp + 1]));
            s_f[(pr * 5 + pxp) * 64 + co] = fmaxf(m + b2r, 0.f);
        }
    }
    __syncthreads();

    // ---- Phase D: gate logits (f @ gw + gb) ----
    {
        float gl[NE] = {0.f, 0.f, 0.f, 0.f, 0.f};
        for (int d = t; d < 1600; d += NT) {
            const float fd = s_f[d];
            #pragma unroll
            for (int e = 0; e < NE; e++) gl[e] = fmaf(fd, gw[d * NE + e], gl[e]);
        }
        #pragma unroll
        for (int e = 0; e < NE; e++) {
            #pragma unroll
            for (int off = 32; off; off >>= 1) gl[e] += __shfl_down(gl[e], off, 64);
        }
        if (lane == 0) {
            #pragma unroll
            for (int e = 0; e < NE; e++) s_red[wv * NE + e] = gl[e];
        }
    }
    __syncthreads();
    if (t == 0) {
        #pragma unroll
        for (int e = 0; e < NE; e++) {
            float s = gb[e];
            #pragma unroll
            for (int w_ = 0; w_ < 5; w_++) s += s_red[w_ * NE + e];
            s_gate[e] = s;
        }
    }
    __syncthreads();

    // ---- Phase E: softmax over 5 + stable top-3 (uniform per thread) ----
    int   idxk[NK];
    float wk[NK];
    {
        float gv[NE], pe[NE];
        #pragma unroll
        for (int e = 0; e < NE; e++) gv[e] = s_gate[e];
        float mg = gv[0];
        #pragma unroll
        for (int e = 1; e < NE; e++) mg = fmaxf(mg, gv[e]);
        float se = 0.f;
        #pragma unroll
        for (int e = 0; e < NE; e++) { pe[e] = expf(gv[e] - mg); se += pe[e]; }
        const float inv = 1.f / se;
        #pragma unroll
        for (int e = 0; e < NE; e++) pe[e] *= inv;
        bool used[NE] = {false, false, false, false, false};
        #pragma unroll
        for (int k = 0; k < NK; k++) {
            int bi = 0; float bv = -1e30f;
            #pragma unroll
            for (int e = 0; e < NE; e++)
                if (!used[e] && pe[e] > bv) { bv = pe[e]; bi = e; }  // strict >: lowest idx wins ties
            used[bi] = true; idxk[k] = bi; wk[k] = bv;
        }
    }

    // ---- Phase F: top-3 expert GEMVs, weighted sum, softmax(10) ----
    {
        float a10[NC];
        #pragma unroll
        for (int h = 0; h < NC; h++) a10[h] = 0.f;
        for (int d = t; d < 1600; d += NT) {
            const float fd = s_f[d];
            #pragma unroll
            for (int k = 0; k < NK; k++) {
                const float* ep = ew + (idxk[k] * 1600 + d) * NC;
                const float wf = wk[k] * fd;
                #pragma unroll
                for (int h = 0; h < NC; h++) a10[h] = fmaf(wf, ep[h], a10[h]);
            }
        }
        #pragma unroll
        for (int h = 0; h < NC; h++) {
            #pragma unroll
            for (int off = 32; off; off >>= 1) a10[h] += __shfl_down(a10[h], off, 64);
        }
        if (lane == 0) {
            #pragma unroll
            for (int h = 0; h < NC; h++) s_red[wv * NC + h] = a10[h];
        }
        __syncthreads();
        if (t == 0) {
            float c10[NC];
            #pragma unroll
            for (int h = 0; h < NC; h++) {
                float s = 0.f;
                #pragma unroll
                for (int w_ = 0; w_ < 5; w_++) s += s_red[w_ * NC + h];
                c10[h] = s;
            }
            #pragma unroll
            for (int k = 0; k < NK; k++)
                #pragma unroll
                for (int h = 0; h < NC; h++)
                    c10[h] = fmaf(wk[k], eb[idxk[k] * NC + h], c10[h]);
            float mx = c10[0];
            #pragma unroll
            for (int h = 1; h < NC; h++) mx = fmaxf(mx, c10[h]);
            float se = 0.f;
            #pragma unroll
            for (int h = 0; h < NC; h++) { c10[h] = expf(c10[h] - mx); se += c10[h]; }
            const float inv = 1.f / se;
            #pragma unroll
            for (int h = 0; h < NC; h++) out[b * NC + h] = c10[h] * inv;
        }
    }
}

extern "C" void kernel_launch(void* const* d_in, const int* in_sizes, int n_in,
                              void* d_out, int out_size, void* d_ws, size_t ws_size,
                              hipStream_t stream) {
    const float* x   = (const float*)d_in[0];
    const float* w1  = (const float*)d_in[1];
    const float* b1  = (const float*)d_in[2];
    const float* w2  = (const float*)d_in[3];
    const float* b2  = (const float*)d_in[4];
    const float* gw  = (const float*)d_in[5];
    const float* gb  = (const float*)d_in[6];
    const float* ew  = (const float*)d_in[7];
    const float* eb  = (const float*)d_in[8];
    float* out = (float*)d_out;

    const int batch = in_sizes[0] / 784;   // 8192
    moe_fused<<<batch, NT, 0, stream>>>(x, w1, b1, w2, b2, gw, gb, ew, eb, out);
}

// Round 6
// 864.579 us; speedup vs baseline: 1.2454x; 1.0043x over previous
//
#include <hip/hip_runtime.h>
#include <math.h>

#define NE 5
#define NK 3
#define NC 10
#define NT 320   // 5 waves: one wave per pooled output row in conv2

// One block per image.
// LDS: img 784 + w1 288 + b1 32 + p1 5408 + f 1600 + red 64 + gate 8 = 8184 f ~= 32.7 KB.
// waves_per_eu PINNED at (4,4): with min-only hints the allocator is unstable across
// toolchains — R4 gave 48 VGPR (130 MB scratch spill), R5 gave 60 VGPR (prefetch
// serialized, 868 us). Pinning max=4 removes the incentive to squeeze below the
// 128-reg budget; R3's 96-reg compile ran 379 us.
__attribute__((amdgpu_flat_work_group_size(NT, NT), amdgpu_waves_per_eu(4, 4)))
__global__ void moe_fused(const float* __restrict__ x,
                          const float* __restrict__ w1, const float* __restrict__ b1,
                          const float* __restrict__ w2, const float* __restrict__ b2,
                          const float* __restrict__ gw, const float* __restrict__ gb,
                          const float* __restrict__ ew, const float* __restrict__ eb,
                          float* __restrict__ out)
{
    __shared__ float s_img[784];    // [28][28]
    __shared__ float s_w1[288];     // [3][3][32]
    __shared__ float s_b1[32];
    __shared__ float s_p1[5408];    // [ci=32][169]  channel-major: conv2 reads are wave-broadcast
    __shared__ float s_f[1600];     // [5][5][64] == flatten order
    __shared__ float s_red[64];
    __shared__ float s_gate[8];

    const int t = threadIdx.x;
    const int b = blockIdx.x;
    const int lane = t & 63;
    const int wv = t >> 6;          // 0..4

    // ---- Phase A: stage image + conv1 weights ----
    for (int i = t; i < 784; i += NT) s_img[i] = x[b * 784 + i];
    for (int i = t; i < 288; i += NT) s_w1[i] = w1[i];
    if (t < 32) s_b1[t] = b1[t];
    __syncthreads();

    // ---- Phase B: conv1 + relu + maxpool2 -> s_p1[co][13*13] ----
    {
        const int co = t & 31;
        float w1r[9];
        #pragma unroll
        for (int k = 0; k < 9; k++) w1r[k] = s_w1[k * 32 + co];
        const float b1r = s_b1[co];
        for (int o = t; o < 5408; o += NT) {
            const int pos = o >> 5;            // (o&31)==co since NT%32==0
            const int py = pos / 13, px = pos % 13;
            // register-cache the 4x4 pixel patch (wave-broadcast LDS reads)
            float p[4][4];
            #pragma unroll
            for (int dy = 0; dy < 4; dy++)
            #pragma unroll
            for (int dx = 0; dx < 4; dx++)
                p[dy][dx] = s_img[(2 * py + dy) * 28 + (2 * px + dx)];
            float m = -1e30f;
            #pragma unroll
            for (int dy = 0; dy < 2; dy++)
            #pragma unroll
            for (int dx = 0; dx < 2; dx++) {
                float s = b1r;
                #pragma unroll
                for (int ky = 0; ky < 3; ky++)
                #pragma unroll
                for (int kx = 0; kx < 3; kx++)
                    s = fmaf(p[dy + ky][dx + kx], w1r[ky * 3 + kx], s);
                m = fmaxf(m, s);
            }
            s_p1[co * 169 + pos] = fmaxf(m, 0.f);   // relu(max)==max(relu)
        }
    }
    __syncthreads();

    // ---- Phase C: conv2 + relu + maxpool2 -> s_f[5][5][64] ----
    // wave wv owns pooled row pr=wv; thread owns output channel co=lane.
    // Register sliding window: 12-col input row reused across 3 kx and 2 conv rows.
    {
        const int co = lane;
        const int pr = wv;                       // pooled row 0..4
        const float* __restrict__ wp = w2 + co;  // w2[((ky*3+kx)*32+ci)*64 + co]
        float acc[2][10];
        #pragma unroll
        for (int cy = 0; cy < 2; cy++)
            #pragma unroll
            for (int px = 0; px < 10; px++) acc[cy][px] = 0.f;

        float w[9], wn[9];
        #pragma unroll
        for (int k = 0; k < 9; k++) w[k] = wp[(k * 32) * 64];
        const int pbase0 = 2 * pr * 13;

        #pragma unroll 1
        for (int ci = 0; ci < 32; ci++) {
            if (ci < 31) {                       // prefetch next ci's 9 weights
                #pragma unroll
                for (int k = 0; k < 9; k++) wn[k] = wp[(k * 32 + ci + 1) * 64];
            }
            const int pb = ci * 169 + pbase0;
            #pragma unroll
            for (int r = 0; r < 4; r++) {        // input rows 2pr..2pr+3
                float in[12];
                #pragma unroll
                for (int xx = 0; xx < 12; xx++) in[xx] = s_p1[pb + r * 13 + xx];
                #pragma unroll
                for (int cy = 0; cy < 2; cy++) {
                    const int ky = r - cy;       // compile-time after unroll
                    if (0 <= ky && ky < 3) {
                        #pragma unroll
                        for (int kx = 0; kx < 3; kx++) {
                            const float wv_ = w[ky * 3 + kx];
                            #pragma unroll
                            for (int px = 0; px < 10; px++)
                                acc[cy][px] = fmaf(in[px + kx], wv_, acc[cy][px]);
                        }
                    }
                }
            }
            if (ci < 31) {
                #pragma unroll
                for (int k = 0; k < 9; k++) w[k] = wn[k];
            }
        }
        const float b2r = b2[co];
        #pragma unroll
        for (int pxp = 0; pxp < 5; pxp++) {
            float m = fmaxf(fmaxf(acc[0][2 * pxp], acc[0][2 * pxp + 1]),
                            fmaxf(acc[1][2 * pxp], acc[1][2 * pxp + 1]));
            s_f[(pr * 5 + pxp) * 64 + co] = fmaxf(m + b2r, 0.f);
        }
    }
    __syncthreads();

    // ---- Phase D: gate logits (f @ gw + gb) ----
    {
        float gl[NE] = {0.f, 0.f, 0.f, 0.f, 0.f};
        for (int d = t; d < 1600; d += NT) {
            const float fd = s_f[d];
            #pragma unroll
            for (int e = 0; e < NE; e++) gl[e] = fmaf(fd, gw[d * NE + e], gl[e]);
        }
        #pragma unroll
        for (int e = 0; e < NE; e++) {
            #pragma unroll
            for (int off = 32; off; off >>= 1) gl[e] += __shfl_down(gl[e], off, 64);
        }
        if (lane == 0) {
            #pragma unroll
            for (int e = 0; e < NE; e++) s_red[wv * NE + e] = gl[e];
        }
    }
    __syncthreads();
    if (t == 0) {
        #pragma unroll
        for (int e = 0; e < NE; e++) {
            float s = gb[e];
            #pragma unroll
            for (int w_ = 0; w_ < 5; w_++) s += s_red[w_ * NE + e];
            s_gate[e] = s;
        }
    }
    __syncthreads();

    // ---- Phase E: softmax over 5 + stable top-3 (uniform per thread) ----
    int   idxk[NK];
    float wk[NK];
    {
        float gv[NE], pe[NE];
        #pragma unroll
        for (int e = 0; e < NE; e++) gv[e] = s_gate[e];
        float mg = gv[0];
        #pragma unroll
        for (int e = 1; e < NE; e++) mg = fmaxf(mg, gv[e]);
        float se = 0.f;
        #pragma unroll
        for (int e = 0; e < NE; e++) { pe[e] = expf(gv[e] - mg); se += pe[e]; }
        const float inv = 1.f / se;
        #pragma unroll
        for (int e = 0; e < NE; e++) pe[e] *= inv;
        bool used[NE] = {false, false, false, false, false};
        #pragma unroll
        for (int k = 0; k < NK; k++) {
            int bi = 0; float bv = -1e30f;
            #pragma unroll
            for (int e = 0; e < NE; e++)
                if (!used[e] && pe[e] > bv) { bv = pe[e]; bi = e; }  // strict >: lowest idx wins ties
            used[bi] = true; idxk[k] = bi; wk[k] = bv;
        }
    }

    // ---- Phase F: top-3 expert GEMVs, weighted sum, softmax(10) ----
    {
        float a10[NC];
        #pragma unroll
        for (int h = 0; h < NC; h++) a10[h] = 0.f;
        for (int d = t; d < 1600; d += NT) {
            const float fd = s_f[d];
            #pragma unroll
            for (int k = 0; k < NK; k++) {
                const float* ep = ew + (idxk[k] * 1600 + d) * NC;
                const float wf = wk[k] * fd;
                #pragma unroll
                for (int h = 0; h < NC; h++) a10[h] = fmaf(wf, ep[h], a10[h]);
            }
        }
        #pragma unroll
        for (int h = 0; h < NC; h++) {
            #pragma unroll
            for (int off = 32; off; off >>= 1) a10[h] += __shfl_down(a10[h], off, 64);
        }
        if (lane == 0) {
            #pragma unroll
            for (int h = 0; h < NC; h++) s_red[wv * NC + h] = a10[h];
        }
        __syncthreads();
        if (t == 0) {
            float c10[NC];
            #pragma unroll
            for (int h = 0; h < NC; h++) {
                float s = 0.f;
                #pragma unroll
                for (int w_ = 0; w_ < 5; w_++) s += s_red[w_ * NC + h];
                c10[h] = s;
            }
            #pragma unroll
            for (int k = 0; k < NK; k++)
                #pragma unroll
                for (int h = 0; h < NC; h++)
                    c10[h] = fmaf(wk[k], eb[idxk[k] * NC + h], c10[h]);
            float mx = c10[0];
            #pragma unroll
            for (int h = 1; h < NC; h++) mx = fmaxf(mx, c10[h]);
            float se = 0.f;
            #pragma unroll
            for (int h = 0; h < NC; h++) { c10[h] = expf(c10[h] - mx); se += c10[h]; }
            const float inv = 1.f / se;
            #pragma unroll
            for (int h = 0; h < NC; h++) out[b * NC + h] = c10[h] * inv;
        }
    }
}

extern "C" void kernel_launch(void* const* d_in, const int* in_sizes, int n_in,
                              void* d_out, int out_size, void* d_ws, size_t ws_size,
                              hipStream_t stream) {
    const float* x   = (const float*)d_in[0];
    const float* w1  = (const float*)d_in[1];
    const float* b1  = (const float*)d_in[2];
    const float* w2  = (const float*)d_in[3];
    const float* b2  = (const float*)d_in[4];
    const float* gw  = (const float*)d_in[5];
    const float* gb  = (const float*)d_in[6];
    const float* ew  = (const float*)d_in[7];
    const float* eb  = (const float*)d_in[8];
    float* out = (float*)d_out;

    const int batch = in_sizes[0] / 784;   // 8192
    moe_fused<<<batch, NT, 0, stream>>>(x, w1, b1, w2, b2, gw, gb, ew, eb, out);
}

// Round 9
// 397.154 us; speedup vs baseline: 2.7111x; 2.1769x over previous
//
#include <hip/hip_runtime.h>
#include <math.h>

#define NE 5
#define NK 3
#define NC 10
#define NT 512   // 8 waves

typedef __attribute__((ext_vector_type(8)))  short s16x8;   // 8 bf16 (4 VGPR) MFMA A/B frag
typedef __attribute__((ext_vector_type(16))) float f32x16;  // 32x32 MFMA C/D frag

__device__ __forceinline__ unsigned short f2bf(float f) {   // RNE float->bf16
    union { float f; unsigned u; } v; v.f = f;
    unsigned r = v.u + 0x7FFFu + ((v.u >> 16) & 1u);
    return (unsigned short)(r >> 16);
}
__device__ __forceinline__ float bf2f(unsigned short s) {
    union { unsigned u; float f; } v; v.u = ((unsigned)s) << 16;
    return v.f;
}

// One block per image, 512 threads (8 waves).
// conv2 via mfma_f32_32x32x16_bf16: 9 shifted GEMMs [100x32]x[32x64], K=288 total.
// LDS ~70KB -> 2 blocks/CU (16 waves/CU).
// A/B frag layout (std CDNA): lane holds row/col = lane&31, k = (lane>>5)*8+j.
// C/D layout (guide m74/m101): col = lane&31, row = (reg&3)+8*(reg>>2)+4*(lane>>5).
// LDS 16B-slot XOR swizzle (slot ^= (row>>1)&3): 8 consecutive rows cover all 32
// banks -> ~4-way conflict on ds_read_b128 instead of 16-way at 64B pitch.
__attribute__((amdgpu_flat_work_group_size(NT, NT)))
__global__ void moe_fused(const float* __restrict__ x,
                          const float* __restrict__ w1, const float* __restrict__ b1,
                          const float* __restrict__ w2, const float* __restrict__ b2,
                          const float* __restrict__ gw, const float* __restrict__ gb,
                          const float* __restrict__ ew, const float* __restrict__ eb,
                          float* __restrict__ out)
{
    __shared__ float          s_img[784];        // [28][28] f32
    __shared__ float          s_w1[288];         // [3][3][32] f32
    __shared__ float          s_b1[32];
    __shared__ unsigned short s_p1b[169 * 32];   // [arow<169][ci<32] bf16, swizzled
    __shared__ unsigned short s_w2t[9 * 64 * 32];// [kk][co][ci] bf16, swizzled
    __shared__ unsigned short s_c2b[100 * 64];   // conv2 raw out bf16 [p<100][co]
    __shared__ float          s_f[1600];         // [5][5][64] f32 == flatten order
    __shared__ float          s_red[8 * NC];
    __shared__ float          s_gate[NE];

    const int t    = threadIdx.x;
    const int b    = blockIdx.x;
    const int lane = t & 63;
    const int wv   = t >> 6;        // 0..7

    // ---- Phase A: stage image, conv1 weights, W2 -> bf16 transposed [kk][co][ci] ----
    for (int i = t; i < 784; i += NT) s_img[i] = x[b * 784 + i];
    for (int i = t; i < 288; i += NT) s_w1[i] = w1[i];
    if (t < 32) s_b1[t] = b1[t];
    for (int i = t; i < 9 * 32 * 64; i += NT) {          // i = (kk*32+ci)*64+co (coalesced)
        const int kk = i >> 11, rem = i & 2047;
        const int ci = rem >> 6, co = rem & 63;
        const int slot = (ci >> 3) ^ ((co >> 1) & 3);
        s_w2t[kk * 2048 + co * 32 + slot * 8 + (ci & 7)] = f2bf(w2[i]);
    }
    __syncthreads();

    // ---- Phase B: conv1 (fp32) + relu + maxpool2 -> s_p1b bf16 [pos][ci] swizzled ----
    {
        const int co = t & 31;                 // NT%32==0 -> constant across o-loop
        float w1r[9];
        #pragma unroll
        for (int k = 0; k < 9; k++) w1r[k] = s_w1[k * 32 + co];
        const float b1r = s_b1[co];
        for (int o = t; o < 5408; o += NT) {
            const int pos = o >> 5;
            const int py = pos / 13, px = pos % 13;
            float p[4][4];
            #pragma unroll
            for (int dy = 0; dy < 4; dy++)
            #pragma unroll
            for (int dx = 0; dx < 4; dx++)
                p[dy][dx] = s_img[(2 * py + dy) * 28 + (2 * px + dx)];
            float m = -1e30f;
            #pragma unroll
            for (int dy = 0; dy < 2; dy++)
            #pragma unroll
            for (int dx = 0; dx < 2; dx++) {
                float s = b1r;
                #pragma unroll
                for (int ky = 0; ky < 3; ky++)
                #pragma unroll
                for (int kx = 0; kx < 3; kx++)
                    s = fmaf(p[dy + ky][dx + kx], w1r[ky * 3 + kx], s);
                m = fmaxf(m, s);
            }
            const int slot = (co >> 3) ^ ((pos >> 1) & 3);
            s_p1b[pos * 32 + slot * 8 + (co & 7)] = f2bf(fmaxf(m, 0.f));
        }
    }
    __syncthreads();

    // ---- Phase C: conv2 via MFMA. wave w: M-tile mt=w>>1 (32 pos), N-tile nt=w&1 (32 co) ----
    {
        const int mt = wv >> 1, nt = wv & 1;
        const int half = lane >> 5, lm = lane & 31;
        const int p = mt * 32 + lm;                         // output position row of A
        const int arow0 = (p < 100) ? ((p / 10) * 13 + (p % 10)) : 0;  // pad rows read row 0
        const int bco = nt * 32 + lm;
        const int bswz = (bco >> 1) & 3;
        const unsigned short* bbase = s_w2t + bco * 32;

        f32x16 acc;
        #pragma unroll
        for (int i = 0; i < 16; i++) acc[i] = 0.f;

        #pragma unroll
        for (int ky = 0; ky < 3; ky++)
        #pragma unroll
        for (int kx = 0; kx < 3; kx++) {
            const int kk = ky * 3 + kx;
            const int ar = arow0 + ky * 13 + kx;
            const int aswz = (ar >> 1) & 3;
            #pragma unroll
            for (int h = 0; h < 2; h++) {
                const int sp = 2 * h + half;                // 16B slot pre-swizzle
                s16x8 av = *(const s16x8*)&s_p1b[ar * 32 + ((sp ^ aswz) << 3)];
                s16x8 bv = *(const s16x8*)&bbase[kk * 2048 + ((sp ^ bswz) << 3)];
                acc = __builtin_amdgcn_mfma_f32_32x32x16_bf16(av, bv, acc, 0, 0, 0);
            }
        }
        // write raw conv2 (pre-bias) to LDS
        #pragma unroll
        for (int r = 0; r < 16; r++) {
            const int prow = mt * 32 + (r & 3) + 8 * (r >> 2) + 4 * half;
            if (prow < 100) s_c2b[prow * 64 + bco] = f2bf(acc[r]);
        }
    }
    __syncthreads();

    // ---- Phase D: maxpool2 + bias + relu -> s_f fp32 [5][5][64] ----
    for (int i = t; i < 1600; i += NT) {
        const int co = i & 63, pp = i >> 6;
        const int py = pp / 5, px = pp % 5;
        const int p00 = (2 * py * 10 + 2 * px) * 64 + co;
        const float v0 = bf2f(s_c2b[p00]),       v1 = bf2f(s_c2b[p00 + 64]);
        const float v2 = bf2f(s_c2b[p00 + 640]), v3 = bf2f(s_c2b[p00 + 704]);
        const float m = fmaxf(fmaxf(v0, v1), fmaxf(v2, v3));
        s_f[i] = fmaxf(m + b2[co], 0.f);
    }
    __syncthreads();

    // ---- Phase E: gate logits ----
    {
        float gl[NE] = {0.f, 0.f, 0.f, 0.f, 0.f};
        for (int d = t; d < 1600; d += NT) {
            const float fd = s_f[d];
            #pragma unroll
            for (int e = 0; e < NE; e++) gl[e] = fmaf(fd, gw[d * NE + e], gl[e]);
        }
        #pragma unroll
        for (int e = 0; e < NE; e++) {
            #pragma unroll
            for (int off = 32; off; off >>= 1) gl[e] += __shfl_down(gl[e], off, 64);
        }
        if (lane == 0) {
            #pragma unroll
            for (int e = 0; e < NE; e++) s_red[wv * NE + e] = gl[e];
        }
    }
    __syncthreads();
    if (t == 0) {
        #pragma unroll
        for (int e = 0; e < NE; e++) {
            float s = gb[e];
            #pragma unroll
            for (int w_ = 0; w_ < 8; w_++) s += s_red[w_ * NE + e];
            s_gate[e] = s;
        }
    }
    __syncthreads();

    // ---- Phase F: softmax(5) + stable top-3 (uniform per thread) ----
    int   idxk[NK];
    float wk[NK];
    {
        float gv[NE], pe[NE];
        #pragma unroll
        for (int e = 0; e < NE; e++) gv[e] = s_gate[e];
        float mg = gv[0];
        #pragma unroll
        for (int e = 1; e < NE; e++) mg = fmaxf(mg, gv[e]);
        float se = 0.f;
        #pragma unroll
        for (int e = 0; e < NE; e++) { pe[e] = expf(gv[e] - mg); se += pe[e]; }
        const float inv = 1.f / se;
        #pragma unroll
        for (int e = 0; e < NE; e++) pe[e] *= inv;
        bool used[NE] = {false, false, false, false, false};
        #pragma unroll
        for (int k = 0; k < NK; k++) {
            int bi = 0; float bv = -1e30f;
            #pragma unroll
            for (int e = 0; e < NE; e++)
                if (!used[e] && pe[e] > bv) { bv = pe[e]; bi = e; }  // strict >: lowest idx ties
            used[bi] = true; idxk[k] = bi; wk[k] = bv;
        }
    }

    // ---- Phase G: top-3 expert GEMVs, weighted sum, softmax(10) ----
    {
        float a10[NC];
        #pragma unroll
        for (int h = 0; h < NC; h++) a10[h] = 0.f;
        for (int d = t; d < 1600; d += NT) {
            const float fd = s_f[d];
            #pragma unroll
            for (int k = 0; k < NK; k++) {
                const float* ep = ew + (idxk[k] * 1600 + d) * NC;
                const float wf = wk[k] * fd;
                #pragma unroll
                for (int h = 0; h < NC; h++) a10[h] = fmaf(wf, ep[h], a10[h]);
            }
        }
        #pragma unroll
        for (int h = 0; h < NC; h++) {
            #pragma unroll
            for (int off = 32; off; off >>= 1) a10[h] += __shfl_down(a10[h], off, 64);
        }
        if (lane == 0) {
            #pragma unroll
            for (int h = 0; h < NC; h++) s_red[wv * NC + h] = a10[h];
        }
        __syncthreads();
        if (t == 0) {
            float c10[NC];
            #pragma unroll
            for (int h = 0; h < NC; h++) {
                float s = 0.f;
                #pragma unroll
                for (int w_ = 0; w_ < 8; w_++) s += s_red[w_ * NC + h];
                c10[h] = s;
            }
            #pragma unroll
            for (int k = 0; k < NK; k++)
                #pragma unroll
                for (int h = 0; h < NC; h++)
                    c10[h] = fmaf(wk[k], eb[idxk[k] * NC + h], c10[h]);
            float mx = c10[0];
            #pragma unroll
            for (int h = 1; h < NC; h++) mx = fmaxf(mx, c10[h]);
            float se = 0.f;
            #pragma unroll
            for (int h = 0; h < NC; h++) { c10[h] = expf(c10[h] - mx); se += c10[h]; }
            const float inv = 1.f / se;
            #pragma unroll
            for (int h = 0; h < NC; h++) out[b * NC + h] = c10[h] * inv;
        }
    }
}

extern "C" void kernel_launch(void* const* d_in, const int* in_sizes, int n_in,
                              void* d_out, int out_size, void* d_ws, size_t ws_size,
                              hipStream_t stream) {
    const float* x   = (const float*)d_in[0];
    const float* w1  = (const float*)d_in[1];
    const float* b1  = (const float*)d_in[2];
    const float* w2  = (const float*)d_in[3];
    const float* b2  = (const float*)d_in[4];
    const float* gw  = (const float*)d_in[5];
    const float* gb  = (const float*)d_in[6];
    const float* ew  = (const float*)d_in[7];
    const float* eb  = (const float*)d_in[8];
    float* out = (float*)d_out;

    const int batch = in_sizes[0] / 784;   // 8192
    moe_fused<<<batch, NT, 0, stream>>>(x, w1, b1, w2, b2, gw, gb, ew, eb, out);
}

// Round 11
// 317.688 us; speedup vs baseline: 3.3893x; 1.2501x over previous
//
#include <hip/hip_runtime.h>
#include <math.h>

#define NE 5
#define NK 3
#define NC 10
#define NT 512   // 8 waves

typedef __attribute__((ext_vector_type(8)))  short s16x8;   // 8 bf16 (4 VGPR) MFMA A/B frag
typedef __attribute__((ext_vector_type(16))) float f32x16;  // 32x32 MFMA C/D frag

__device__ __forceinline__ unsigned short f2bf(float f) {   // RNE float->bf16
    union { float f; unsigned u; } v; v.f = f;
    unsigned r = v.u + 0x7FFFu + ((v.u >> 16) & 1u);
    return (unsigned short)(r >> 16);
}
__device__ __forceinline__ float bf2f(unsigned short s) {
    union { unsigned u; float f; } v; v.u = ((unsigned)s) << 16;
    return v.f;
}

// ---- Prep kernel (runs every launch, ~2us): W2 fp32 [kk][ci][co] -> bf16 MFMA
// B-fragments in d_ws, layout [kk][nt][h][lane][8]: lane gets col=nt*32+(lane&31),
// k-slice ci = h*16 + (lane>>5)*8 + j. Main kernel loads 16B/lane coalesced from L2.
__global__ void prep_w2(const float* __restrict__ w2, unsigned short* __restrict__ wsW) {
    const int idx = blockIdx.x * 256 + threadIdx.x;
    if (idx >= 18432) return;
    const int j    = idx & 7;
    const int lane = (idx >> 3) & 63;
    const int h    = (idx >> 9) & 1;
    const int nt   = (idx >> 10) & 1;
    const int kk   = idx >> 11;
    const int ci   = h * 16 + ((lane >> 5) << 3) + j;
    const int co   = nt * 32 + (lane & 31);
    wsW[idx] = f2bf(w2[(kk * 32 + ci) * 64 + co]);
}

// One block per image, 512 threads (8 waves).
// conv2 via mfma_f32_32x32x16_bf16: 9 shifted GEMMs [100x32]x[32x64], K=288.
// W2 B-frags come straight from d_ws (L2-resident, 36KB) -> no W2 LDS, no per-block
// transform (was 220 instr/thread + 4-way scatter conflicts at 8192 blocks).
// LDS ~35KB -> 4 blocks/CU.
// A frag: lane holds row=lane&31, k=(lane>>5)*8+j. C/D: col=lane&31,
// row=(reg&3)+8*(reg>>2)+4*(lane>>5)  (guide m74/m101).
__attribute__((amdgpu_flat_work_group_size(NT, NT)))
__global__ void moe_fused(const float* __restrict__ x,
                          const float* __restrict__ w1, const float* __restrict__ b1,
                          const unsigned short* __restrict__ wsW, const float* __restrict__ b2,
                          const float* __restrict__ gw, const float* __restrict__ gb,
                          const float* __restrict__ ew, const float* __restrict__ eb,
                          float* __restrict__ out)
{
    __shared__ float          s_img[784];        // [28][28] f32
    __shared__ float          s_w1[288];         // [3][3][32] f32
    __shared__ float          s_b1[32];
    __shared__ unsigned short s_p1b[169 * 32];   // [arow<169][ci<32] bf16, swizzled
    __shared__ unsigned short s_c2b[100 * 64];   // conv2 raw out bf16 [p<100][co]
    __shared__ float          s_f[1600];         // [5][5][64] f32 == flatten order
    __shared__ float          s_red[8 * NC];
    __shared__ float          s_gate[NE];

    const int t    = threadIdx.x;
    const int b    = blockIdx.x;
    const int lane = t & 63;
    const int wv   = t >> 6;        // 0..7

    // ---- Phase A: stage image + conv1 weights ----
    for (int i = t; i < 784; i += NT) s_img[i] = x[b * 784 + i];
    for (int i = t; i < 288; i += NT) s_w1[i] = w1[i];
    if (t < 32) s_b1[t] = b1[t];
    __syncthreads();

    // ---- Phase B: conv1 (fp32) + relu + maxpool2 -> s_p1b bf16 [pos][ci] swizzled ----
    {
        const int co = t & 31;                 // NT%32==0 -> constant across o-loop
        float w1r[9];
        #pragma unroll
        for (int k = 0; k < 9; k++) w1r[k] = s_w1[k * 32 + co];
        const float b1r = s_b1[co];
        for (int o = t; o < 5408; o += NT) {
            const int pos = o >> 5;
            const int py = pos / 13, px = pos % 13;
            float p[4][4];
            #pragma unroll
            for (int dy = 0; dy < 4; dy++)
            #pragma unroll
            for (int dx = 0; dx < 4; dx++)
                p[dy][dx] = s_img[(2 * py + dy) * 28 + (2 * px + dx)];
            float m = -1e30f;
            #pragma unroll
            for (int dy = 0; dy < 2; dy++)
            #pragma unroll
            for (int dx = 0; dx < 2; dx++) {
                float s = b1r;
                #pragma unroll
                for (int ky = 0; ky < 3; ky++)
                #pragma unroll
                for (int kx = 0; kx < 3; kx++)
                    s = fmaf(p[dy + ky][dx + kx], w1r[ky * 3 + kx], s);
                m = fmaxf(m, s);
            }
            const int slot = (co >> 3) ^ ((pos >> 1) & 3);
            s_p1b[pos * 32 + slot * 8 + (co & 7)] = f2bf(fmaxf(m, 0.f));
        }
    }
    __syncthreads();

    // ---- Phase C: conv2 via MFMA. wave w: M-tile mt=w>>1 (32 pos), N-tile nt=w&1 (32 co) ----
    {
        const int mt = wv >> 1, nt = wv & 1;
        const int half = lane >> 5, lm = lane & 31;
        const int p = mt * 32 + lm;                         // output position row of A
        const int arow0 = (p < 100) ? ((p / 10) * 13 + (p % 10)) : 0;  // pad rows read row 0
        const int bco = nt * 32 + lm;

        f32x16 acc;
        #pragma unroll
        for (int i = 0; i < 16; i++) acc[i] = 0.f;

        #pragma unroll
        for (int ky = 0; ky < 3; ky++)
        #pragma unroll
        for (int kx = 0; kx < 3; kx++) {
            const int kk = ky * 3 + kx;
            const int ar = arow0 + ky * 13 + kx;
            const int aswz = (ar >> 1) & 3;
            #pragma unroll
            for (int h = 0; h < 2; h++) {
                const int sp = 2 * h + half;                // 16B slot pre-swizzle
                s16x8 av = *(const s16x8*)&s_p1b[ar * 32 + ((sp ^ aswz) << 3)];
                s16x8 bv = *(const s16x8*)&wsW[((((kk * 2 + nt) * 2 + h) * 64) + lane) * 8];
                acc = __builtin_amdgcn_mfma_f32_32x32x16_bf16(av, bv, acc, 0, 0, 0);
            }
        }
        // write raw conv2 (pre-bias) to LDS
        #pragma unroll
        for (int r = 0; r < 16; r++) {
            const int prow = mt * 32 + (r & 3) + 8 * (r >> 2) + 4 * half;
            if (prow < 100) s_c2b[prow * 64 + bco] = f2bf(acc[r]);
        }
    }
    __syncthreads();

    // ---- Phase D: maxpool2 + bias + relu -> s_f fp32 [5][5][64] ----
    for (int i = t; i < 1600; i += NT) {
        const int co = i & 63, pp = i >> 6;
        const int py = pp / 5, px = pp % 5;
        const int p00 = (2 * py * 10 + 2 * px) * 64 + co;
        const float v0 = bf2f(s_c2b[p00]),       v1 = bf2f(s_c2b[p00 + 64]);
        const float v2 = bf2f(s_c2b[p00 + 640]), v3 = bf2f(s_c2b[p00 + 704]);
        const float m = fmaxf(fmaxf(v0, v1), fmaxf(v2, v3));
        s_f[i] = fmaxf(m + b2[co], 0.f);
    }
    __syncthreads();

    // ---- Phase E: gate logits ----
    {
        float gl[NE] = {0.f, 0.f, 0.f, 0.f, 0.f};
        for (int d = t; d < 1600; d += NT) {
            const float fd = s_f[d];
            #pragma unroll
            for (int e = 0; e < NE; e++) gl[e] = fmaf(fd, gw[d * NE + e], gl[e]);
        }
        #pragma unroll
        for (int e = 0; e < NE; e++) {
            #pragma unroll
            for (int off = 32; off; off >>= 1) gl[e] += __shfl_down(gl[e], off, 64);
        }
        if (lane == 0) {
            #pragma unroll
            for (int e = 0; e < NE; e++) s_red[wv * NE + e] = gl[e];
        }
    }
    __syncthreads();
    if (t == 0) {
        #pragma unroll
        for (int e = 0; e < NE; e++) {
            float s = gb[e];
            #pragma unroll
            for (int w_ = 0; w_ < 8; w_++) s += s_red[w_ * NE + e];
            s_gate[e] = s;
        }
    }
    __syncthreads();

    // ---- Phase F: softmax(5) + stable top-3 (uniform per thread) ----
    int   idxk[NK];
    float wk[NK];
    {
        float gv[NE], pe[NE];
        #pragma unroll
        for (int e = 0; e < NE; e++) gv[e] = s_gate[e];
        float mg = gv[0];
        #pragma unroll
        for (int e = 1; e < NE; e++) mg = fmaxf(mg, gv[e]);
        float se = 0.f;
        #pragma unroll
        for (int e = 0; e < NE; e++) { pe[e] = expf(gv[e] - mg); se += pe[e]; }
        const float inv = 1.f / se;
        #pragma unroll
        for (int e = 0; e < NE; e++) pe[e] *= inv;
        bool used[NE] = {false, false, false, false, false};
        #pragma unroll
        for (int k = 0; k < NK; k++) {
            int bi = 0; float bv = -1e30f;
            #pragma unroll
            for (int e = 0; e < NE; e++)
                if (!used[e] && pe[e] > bv) { bv = pe[e]; bi = e; }  // strict >: lowest idx ties
            used[bi] = true; idxk[k] = bi; wk[k] = bv;
        }
    }

    // ---- Phase G: top-3 expert GEMVs, weighted sum, softmax(10) ----
    {
        float a10[NC];
        #pragma unroll
        for (int h = 0; h < NC; h++) a10[h] = 0.f;
        for (int d = t; d < 1600; d += NT) {
            const float fd = s_f[d];
            #pragma unroll
            for (int k = 0; k < NK; k++) {
                const float* ep = ew + (idxk[k] * 1600 + d) * NC;
                const float wf = wk[k] * fd;
                #pragma unroll
                for (int h = 0; h < NC; h++) a10[h] = fmaf(wf, ep[h], a10[h]);
            }
        }
        #pragma unroll
        for (int h = 0; h < NC; h++) {
            #pragma unroll
            for (int off = 32; off; off >>= 1) a10[h] += __shfl_down(a10[h], off, 64);
        }
        if (lane == 0) {
            #pragma unroll
            for (int h = 0; h < NC; h++) s_red[wv * NC + h] = a10[h];
        }
        __syncthreads();
        if (t == 0) {
            float c10[NC];
            #pragma unroll
            for (int h = 0; h < NC; h++) {
                float s = 0.f;
                #pragma unroll
                for (int w_ = 0; w_ < 8; w_++) s += s_red[w_ * NC + h];
                c10[h] = s;
            }
            #pragma unroll
            for (int k = 0; k < NK; k++)
                #pragma unroll
                for (int h = 0; h < NC; h++)
                    c10[h] = fmaf(wk[k], eb[idxk[k] * NC + h], c10[h]);
            float mx = c10[0];
            #pragma unroll
            for (int h = 1; h < NC; h++) mx = fmaxf(mx, c10[h]);
            float se = 0.f;
            #pragma unroll
            for (int h = 0; h < NC; h++) { c10[h] = expf(c10[h] - mx); se += c10[h]; }
            const float inv = 1.f / se;
            #pragma unroll
            for (int h = 0; h < NC; h++) out[b * NC + h] = c10[h] * inv;
        }
    }
}

extern "C" void kernel_launch(void* const* d_in, const int* in_sizes, int n_in,
                              void* d_out, int out_size, void* d_ws, size_t ws_size,
                              hipStream_t stream) {
    const float* x   = (const float*)d_in[0];
    const float* w1  = (const float*)d_in[1];
    const float* b1  = (const float*)d_in[2];
    const float* w2  = (const float*)d_in[3];
    const float* b2  = (const float*)d_in[4];
    const float* gw  = (const float*)d_in[5];
    const float* gb  = (const float*)d_in[6];
    const float* ew  = (const float*)d_in[7];
    const float* eb  = (const float*)d_in[8];
    float* out = (float*)d_out;
    unsigned short* wsW = (unsigned short*)d_ws;   // 18432 bf16 = 36 KB

    prep_w2<<<72, 256, 0, stream>>>(w2, wsW);

    const int batch = in_sizes[0] / 784;   // 8192
    moe_fused<<<batch, NT, 0, stream>>>(x, w1, b1, wsW, b2, gw, gb, ew, eb, out);
}

// Round 12
// 311.561 us; speedup vs baseline: 3.4559x; 1.0197x over previous
//
#include <hip/hip_runtime.h>
#include <math.h>

#define NE 5
#define NK 3
#define NC 10
#define NT 512   // 8 waves

typedef __attribute__((ext_vector_type(8)))  short s16x8;   // 8 bf16 (4 VGPR) MFMA A/B frag
typedef __attribute__((ext_vector_type(16))) float f32x16;  // 32x32 MFMA C/D frag

__device__ __forceinline__ unsigned short f2bf(float f) {   // RNE float->bf16
    union { float f; unsigned u; } v; v.f = f;
    unsigned r = v.u + 0x7FFFu + ((v.u >> 16) & 1u);
    return (unsigned short)(r >> 16);
}
__device__ __forceinline__ float bf2f(unsigned short s) {
    union { unsigned u; float f; } v; v.u = ((unsigned)s) << 16;
    return v.f;
}

// ---- Prep kernel (~2us/launch): weights -> bf16 MFMA B-fragments in d_ws.
// [0, 18432): W2 frags [kk][nt][h][lane][8]: col=nt*32+(lane&31), ci=h*16+(lane>>5)*8+j.
// [18432, 18944): W1 frag (K=9 padded to 16): col=lane&31, k=(lane>>5)*8+j, 0 for k>=9.
__global__ void prep_w(const float* __restrict__ w2, const float* __restrict__ w1,
                       unsigned short* __restrict__ wsW) {
    const int idx = blockIdx.x * 256 + threadIdx.x;
    if (idx < 18432) {
        const int j    = idx & 7;
        const int lane = (idx >> 3) & 63;
        const int h    = (idx >> 9) & 1;
        const int nt   = (idx >> 10) & 1;
        const int kk   = idx >> 11;
        const int ci   = h * 16 + ((lane >> 5) << 3) + j;
        const int co   = nt * 32 + (lane & 31);
        wsW[idx] = f2bf(w2[(kk * 32 + ci) * 64 + co]);
    } else if (idx < 18944) {
        const int i2   = idx - 18432;
        const int j    = i2 & 7;
        const int lane = i2 >> 3;
        const int k    = ((lane >> 5) << 3) + j;
        const int co   = lane & 31;
        wsW[idx] = (k < 9) ? f2bf(w1[k * 32 + co]) : (unsigned short)0;
    }
}

// One block per image, 512 threads (8 waves). LDS ~33.6KB -> 4 blocks/CU.
// conv1 via MFMA: K=9 padded to 16; one 32x32 tile per conv row (A row index = cx,
// rows 26..31 garbage). Wave handles pooled row pair (2py,2py+1) = 2 MFMAs; A frags
// built in registers straight from s_img (no im2col LDS). Pool pairs (2px,2px+1)
// are same-lane adjacent regs (row bit0 == reg bit0); garbage rows 26..31 fall on
// the skipped regs. conv2 via MFMA as R11 (9 shifted [100x32]x[32x64], K=288).
// C/D layout: col=lane&31, row=(reg&3)+8*(reg>>2)+4*(lane>>5)  (guide m74/m101).
__attribute__((amdgpu_flat_work_group_size(NT, NT)))
__global__ void moe_fused(const float* __restrict__ x,
                          const float* __restrict__ b1,
                          const unsigned short* __restrict__ wsW, const float* __restrict__ b2,
                          const float* __restrict__ gw, const float* __restrict__ gb,
                          const float* __restrict__ ew, const float* __restrict__ eb,
                          float* __restrict__ out)
{
    __shared__ float          s_img[800];        // [28][28] f32 (+pad: cx>=26 garbage reads)
    __shared__ unsigned short s_p1b[169 * 32];   // [pos<169][ci<32] bf16, 16B-slot swizzled
    __shared__ unsigned short s_c2b[100 * 64];   // conv2 raw out bf16 [p<100][co]
    __shared__ float          s_f[1600];         // [5][5][64] f32 == flatten order
    __shared__ float          s_red[8 * NC];
    __shared__ float          s_gate[NE];

    const int t    = threadIdx.x;
    const int b    = blockIdx.x;
    const int lane = t & 63;
    const int wv   = t >> 6;        // 0..7

    // ---- Phase A: stage image (float4) ----
    if (t < 196) ((float4*)s_img)[t] = ((const float4*)(x + b * 784))[t];
    __syncthreads();

    // ---- Phase B: conv1 via MFMA + in-register maxpool -> s_p1b ----
    {
        const int cx   = lane & 31;        // A row (position within conv row)
        const int half = lane >> 5;
        const int co   = lane & 31;        // C col (channel)
        s16x8 bw1 = *(const s16x8*)&wsW[18432 + lane * 8];
        const float b1co = b1[co];

        for (int pr = wv; pr < 13; pr += 8) {      // pooled row pair (2pr, 2pr+1)
            s16x8 afA = {0,0,0,0,0,0,0,0}, afB = {0,0,0,0,0,0,0,0};
            if (half == 0) {                        // k = j = 0..8? (0..7 here)
                #pragma unroll
                for (int j = 0; j < 8; j++) {
                    const int ky = j / 3, kx = j % 3;          // compile-time
                    afA[j] = (short)f2bf(s_img[(2 * pr +     ky) * 28 + cx + kx]);
                    afB[j] = (short)f2bf(s_img[(2 * pr + 1 + ky) * 28 + cx + kx]);
                }
            } else {                                // k = 8 only (ky=2,kx=2)
                afA[0] = (short)f2bf(s_img[(2 * pr + 2) * 28 + cx + 2]);
                afB[0] = (short)f2bf(s_img[(2 * pr + 3) * 28 + cx + 2]);
            }
            f32x16 accA, accB;
            #pragma unroll
            for (int i = 0; i < 16; i++) { accA[i] = 0.f; accB[i] = 0.f; }
            accA = __builtin_amdgcn_mfma_f32_32x32x16_bf16(afA, bw1, accA, 0, 0, 0);
            accB = __builtin_amdgcn_mfma_f32_32x32x16_bf16(afB, bw1, accB, 0, 0, 0);

            #pragma unroll
            for (int reg = 0; reg < 16; reg += 2) {
                const int row = (reg & 3) + 8 * (reg >> 2) + 4 * half;   // even
                if (row < 26) {
                    const int px  = row >> 1;
                    const int pos = pr * 13 + px;
                    float m = fmaxf(fmaxf(accA[reg], accA[reg + 1]),
                                    fmaxf(accB[reg], accB[reg + 1]));
                    m = fmaxf(m + b1co, 0.f);
                    const int slot = (co >> 3) ^ ((pos >> 1) & 3);
                    s_p1b[pos * 32 + slot * 8 + (co & 7)] = f2bf(m);
                }
            }
        }
    }
    __syncthreads();

    // ---- Phase C: conv2 via MFMA. wave: M-tile mt=wv>>1 (32 pos), N-tile nt=wv&1 ----
    {
        const int mt = wv >> 1, nt = wv & 1;
        const int half = lane >> 5, lm = lane & 31;
        const int p = mt * 32 + lm;
        const int arow0 = (p < 100) ? ((p / 10) * 13 + (p % 10)) : 0;
        const int bco = nt * 32 + lm;

        f32x16 acc;
        #pragma unroll
        for (int i = 0; i < 16; i++) acc[i] = 0.f;

        #pragma unroll
        for (int ky = 0; ky < 3; ky++)
        #pragma unroll
        for (int kx = 0; kx < 3; kx++) {
            const int kk = ky * 3 + kx;
            const int ar = arow0 + ky * 13 + kx;
            const int aswz = (ar >> 1) & 3;
            #pragma unroll
            for (int h = 0; h < 2; h++) {
                const int sp = 2 * h + half;
                s16x8 av = *(const s16x8*)&s_p1b[ar * 32 + ((sp ^ aswz) << 3)];
                s16x8 bv = *(const s16x8*)&wsW[((((kk * 2 + nt) * 2 + h) * 64) + lane) * 8];
                acc = __builtin_amdgcn_mfma_f32_32x32x16_bf16(av, bv, acc, 0, 0, 0);
            }
        }
        #pragma unroll
        for (int r = 0; r < 16; r++) {
            const int prow = mt * 32 + (r & 3) + 8 * (r >> 2) + 4 * half;
            if (prow < 100) s_c2b[prow * 64 + bco] = f2bf(acc[r]);
        }
    }
    __syncthreads();

    // ---- Phase D: maxpool2 + bias + relu -> s_f fp32 [5][5][64] ----
    for (int i = t; i < 1600; i += NT) {
        const int co = i & 63, pp = i >> 6;
        const int py = pp / 5, px = pp % 5;
        const int p00 = (2 * py * 10 + 2 * px) * 64 + co;
        const float v0 = bf2f(s_c2b[p00]),       v1 = bf2f(s_c2b[p00 + 64]);
        const float v2 = bf2f(s_c2b[p00 + 640]), v3 = bf2f(s_c2b[p00 + 704]);
        const float m = fmaxf(fmaxf(v0, v1), fmaxf(v2, v3));
        s_f[i] = fmaxf(m + b2[co], 0.f);
    }
    __syncthreads();

    // ---- Phase E: gate logits ----
    {
        float gl[NE] = {0.f, 0.f, 0.f, 0.f, 0.f};
        for (int d = t; d < 1600; d += NT) {
            const float fd = s_f[d];
            #pragma unroll
            for (int e = 0; e < NE; e++) gl[e] = fmaf(fd, gw[d * NE + e], gl[e]);
        }
        #pragma unroll
        for (int e = 0; e < NE; e++) {
            #pragma unroll
            for (int off = 32; off; off >>= 1) gl[e] += __shfl_down(gl[e], off, 64);
        }
        if (lane == 0) {
            #pragma unroll
            for (int e = 0; e < NE; e++) s_red[wv * NE + e] = gl[e];
        }
    }
    __syncthreads();
    if (t == 0) {
        #pragma unroll
        for (int e = 0; e < NE; e++) {
            float s = gb[e];
            #pragma unroll
            for (int w_ = 0; w_ < 8; w_++) s += s_red[w_ * NE + e];
            s_gate[e] = s;
        }
    }
    __syncthreads();

    // ---- Phase F: softmax(5) + stable top-3 (uniform per thread) ----
    int   idxk[NK];
    float wk[NK];
    {
        float gv[NE], pe[NE];
        #pragma unroll
        for (int e = 0; e < NE; e++) gv[e] = s_gate[e];
        float mg = gv[0];
        #pragma unroll
        for (int e = 1; e < NE; e++) mg = fmaxf(mg, gv[e]);
        float se = 0.f;
        #pragma unroll
        for (int e = 0; e < NE; e++) { pe[e] = expf(gv[e] - mg); se += pe[e]; }
        const float inv = 1.f / se;
        #pragma unroll
        for (int e = 0; e < NE; e++) pe[e] *= inv;
        bool used[NE] = {false, false, false, false, false};
        #pragma unroll
        for (int k = 0; k < NK; k++) {
            int bi = 0; float bv = -1e30f;
            #pragma unroll
            for (int e = 0; e < NE; e++)
                if (!used[e] && pe[e] > bv) { bv = pe[e]; bi = e; }  // strict >: lowest idx ties
            used[bi] = true; idxk[k] = bi; wk[k] = bv;
        }
    }

    // ---- Phase G: top-3 expert GEMVs, weighted sum, softmax(10) ----
    {
        float a10[NC];
        #pragma unroll
        for (int h = 0; h < NC; h++) a10[h] = 0.f;
        for (int d = t; d < 1600; d += NT) {
            const float fd = s_f[d];
            #pragma unroll
            for (int k = 0; k < NK; k++) {
                const float* ep = ew + (idxk[k] * 1600 + d) * NC;
                const float wf = wk[k] * fd;
                #pragma unroll
                for (int h = 0; h < NC; h++) a10[h] = fmaf(wf, ep[h], a10[h]);
            }
        }
        #pragma unroll
        for (int h = 0; h < NC; h++) {
            #pragma unroll
            for (int off = 32; off; off >>= 1) a10[h] += __shfl_down(a10[h], off, 64);
        }
        if (lane == 0) {
            #pragma unroll
            for (int h = 0; h < NC; h++) s_red[wv * NC + h] = a10[h];
        }
        __syncthreads();
        if (t == 0) {
            float c10[NC];
            #pragma unroll
            for (int h = 0; h < NC; h++) {
                float s = 0.f;
                #pragma unroll
                for (int w_ = 0; w_ < 8; w_++) s += s_red[w_ * NC + h];
                c10[h] = s;
            }
            #pragma unroll
            for (int k = 0; k < NK; k++)
                #pragma unroll
                for (int h = 0; h < NC; h++)
                    c10[h] = fmaf(wk[k], eb[idxk[k] * NC + h], c10[h]);
            float mx = c10[0];
            #pragma unroll
            for (int h = 1; h < NC; h++) mx = fmaxf(mx, c10[h]);
            float se = 0.f;
            #pragma unroll
            for (int h = 0; h < NC; h++) { c10[h] = expf(c10[h] - mx); se += c10[h]; }
            const float inv = 1.f / se;
            #pragma unroll
            for (int h = 0; h < NC; h++) out[b * NC + h] = c10[h] * inv;
        }
    }
}

extern "C" void kernel_launch(void* const* d_in, const int* in_sizes, int n_in,
                              void* d_out, int out_size, void* d_ws, size_t ws_size,
                              hipStream_t stream) {
    const float* x   = (const float*)d_in[0];
    const float* w1  = (const float*)d_in[1];
    const float* b1  = (const float*)d_in[2];
    const float* w2  = (const float*)d_in[3];
    const float* b2  = (const float*)d_in[4];
    const float* gw  = (const float*)d_in[5];
    const float* gb  = (const float*)d_in[6];
    const float* ew  = (const float*)d_in[7];
    const float* eb  = (const float*)d_in[8];
    float* out = (float*)d_out;
    unsigned short* wsW = (unsigned short*)d_ws;   // 18944 bf16 = 37 KB

    prep_w<<<74, 256, 0, stream>>>(w2, w1, wsW);

    const int batch = in_sizes[0] / 784;   // 8192
    moe_fused<<<batch, NT, 0, stream>>>(x, b1, wsW, b2, gw, gb, ew, eb, out);
}

// Round 13
// 275.371 us; speedup vs baseline: 3.9101x; 1.1314x over previous
//
#include <hip/hip_runtime.h>
#include <math.h>

#define NE 5
#define NK 3
#define NC 10
#define NT 512   // 8 waves = 2 image-quads of 4 waves

typedef __attribute__((ext_vector_type(8)))  short s16x8;   // 8 bf16 MFMA A/B frag
typedef __attribute__((ext_vector_type(16))) float f32x16;  // 32x32 MFMA C/D frag

__device__ __forceinline__ unsigned short f2bf(float f) {   // RNE float->bf16
    union { float f; unsigned u; } v; v.f = f;
    unsigned r = v.u + 0x7FFFu + ((v.u >> 16) & 1u);
    return (unsigned short)(r >> 16);
}
__device__ __forceinline__ float bf2f(unsigned short s) {
    union { unsigned u; float f; } v; v.u = ((unsigned)s) << 16;
    return v.f;
}

// ---- Prep kernel: weights -> bf16 MFMA B-fragments in d_ws (unchanged from R11/12).
__global__ void prep_w(const float* __restrict__ w2, const float* __restrict__ w1,
                       unsigned short* __restrict__ wsW) {
    const int idx = blockIdx.x * 256 + threadIdx.x;
    if (idx < 18432) {
        const int j    = idx & 7;
        const int lane = (idx >> 3) & 63;
        const int h    = (idx >> 9) & 1;
        const int nt   = (idx >> 10) & 1;
        const int kk   = idx >> 11;
        const int ci   = h * 16 + ((lane >> 5) << 3) + j;
        const int co   = nt * 32 + (lane & 31);
        wsW[idx] = f2bf(w2[(kk * 32 + ci) * 64 + co]);
    } else if (idx < 18944) {
        const int i2   = idx - 18432;
        const int j    = i2 & 7;
        const int lane = i2 >> 3;
        const int k    = ((lane >> 5) << 3) + j;
        const int co   = lane & 31;
        wsW[idx] = (k < 9) ? f2bf(w1[k * 32 + co]) : (unsigned short)0;
    }
}

// TWO images per 512-thread block (wave-quad per image): same phase pipeline as R12
// but every barrier serves 2 images -> phase/barrier latency per image halved (R12
// post-mortem: all pipes <50% busy at 82% occupancy = barrier-stall-bound).
// conv2: nt-loop inner (A-frag read once, 2 accs). Image + f stored bf16.
// LDS 2x(p1b 9984 + c2b 12800 + f 3200) + red/gate ~= 52.4KB -> 3 blocks/CU.
// p1b capped at 156 rows (conv2 reads ar<=154; pooled row 12 / col 12 never read).
__attribute__((amdgpu_flat_work_group_size(NT, NT)))
__global__ void moe_fused(const float* __restrict__ x,
                          const float* __restrict__ b1,
                          const unsigned short* __restrict__ wsW, const float* __restrict__ b2,
                          const float* __restrict__ gw, const float* __restrict__ gb,
                          const float* __restrict__ ew, const float* __restrict__ eb,
                          float* __restrict__ out)
{
    __shared__ __align__(16) unsigned short s_p1b[2][156 * 32]; // pooled conv1, swizzled
    __shared__ __align__(16) unsigned short s_c2b[2][6400];     // img bf16 (A,B) then conv2 out (C,D)
    __shared__ __align__(16) unsigned short s_fb[2][1600];      // f bf16, flatten order
    __shared__ float s_red[2][4 * NC];
    __shared__ float s_gate[2][8];

    const int t    = threadIdx.x;
    const int lane = t & 63;
    const int wv   = t >> 6;        // 0..7
    const int q    = wv >> 2;       // image slot
    const int w4   = wv & 3;        // wave within quad
    const int tq   = t & 255;       // thread within quad
    const int img  = blockIdx.x * 2 + q;

    // ---- Phase A: stage image as bf16 into c2b region (dead there until conv2 writes) ----
    {
        const float4* xq = (const float4*)(x + img * 784);
        ushort4* dst = (ushort4*)s_c2b[q];
        for (int i = tq; i < 196; i += 256) {
            float4 v = xq[i];
            ushort4 o; o.x = f2bf(v.x); o.y = f2bf(v.y); o.z = f2bf(v.z); o.w = f2bf(v.w);
            dst[i] = o;
        }
    }
    __syncthreads();

    // ---- Phase B: conv1 via MFMA + in-register maxpool -> s_p1b (rows 0..11 only) ----
    {
        const int cx   = lane & 31;
        const int half = lane >> 5;
        const int co   = lane & 31;
        const unsigned short* simg = s_c2b[q];
        s16x8 bw1 = *(const s16x8*)&wsW[18432 + lane * 8];
        const float b1co = b1[co];

        for (int pr = w4; pr < 12; pr += 4) {          // 12 pooled rows / 4 waves = 3 each
            s16x8 afA = {0,0,0,0,0,0,0,0}, afB = {0,0,0,0,0,0,0,0};
            if (half == 0) {
                #pragma unroll
                for (int j = 0; j < 8; j++) {
                    const int ky = j / 3, kx = j % 3;
                    afA[j] = (short)simg[(2 * pr +     ky) * 28 + cx + kx];
                    afB[j] = (short)simg[(2 * pr + 1 + ky) * 28 + cx + kx];
                }
            } else {                                    // k=8 (ky=2,kx=2)
                afA[0] = (short)simg[(2 * pr + 2) * 28 + cx + 2];
                afB[0] = (short)simg[(2 * pr + 3) * 28 + cx + 2];
            }
            f32x16 accA, accB;
            #pragma unroll
            for (int i = 0; i < 16; i++) { accA[i] = 0.f; accB[i] = 0.f; }
            accA = __builtin_amdgcn_mfma_f32_32x32x16_bf16(afA, bw1, accA, 0, 0, 0);
            accB = __builtin_amdgcn_mfma_f32_32x32x16_bf16(afB, bw1, accB, 0, 0, 0);

            #pragma unroll
            for (int reg = 0; reg < 16; reg += 2) {
                const int row = (reg & 3) + 8 * (reg >> 2) + 4 * half;   // even
                if (row < 26) {
                    const int px  = row >> 1;
                    const int pos = pr * 13 + px;                         // <= 155
                    float m = fmaxf(fmaxf(accA[reg], accA[reg + 1]),
                                    fmaxf(accB[reg], accB[reg + 1]));
                    m = fmaxf(m + b1co, 0.f);
                    const int slot = (co >> 3) ^ ((pos >> 1) & 3);
                    s_p1b[q][pos * 32 + slot * 8 + (co & 7)] = f2bf(m);
                }
            }
        }
    }
    __syncthreads();

    // ---- Phase C: conv2 via MFMA. wave w4 = M-tile; nt inner (A read once, 2 accs) ----
    {
        const int mt = w4;
        const int half = lane >> 5, lm = lane & 31;
        const int p = mt * 32 + lm;
        const int arow0 = (p < 100) ? ((p / 10) * 13 + (p % 10)) : 0;

        f32x16 acc0, acc1;
        #pragma unroll
        for (int i = 0; i < 16; i++) { acc0[i] = 0.f; acc1[i] = 0.f; }

        #pragma unroll
        for (int ky = 0; ky < 3; ky++)
        #pragma unroll
        for (int kx = 0; kx < 3; kx++) {
            const int kk = ky * 3 + kx;
            const int ar = arow0 + ky * 13 + kx;       // <= 154
            const int aswz = (ar >> 1) & 3;
            #pragma unroll
            for (int h = 0; h < 2; h++) {
                const int sp = 2 * h + half;
                s16x8 av  = *(const s16x8*)&s_p1b[q][ar * 32 + ((sp ^ aswz) << 3)];
                s16x8 bv0 = *(const s16x8*)&wsW[(((kk * 2 + 0) * 2 + h) * 64 + lane) * 8];
                s16x8 bv1 = *(const s16x8*)&wsW[(((kk * 2 + 1) * 2 + h) * 64 + lane) * 8];
                acc0 = __builtin_amdgcn_mfma_f32_32x32x16_bf16(av, bv0, acc0, 0, 0, 0);
                acc1 = __builtin_amdgcn_mfma_f32_32x32x16_bf16(av, bv1, acc1, 0, 0, 0);
            }
        }
        #pragma unroll
        for (int r = 0; r < 16; r++) {
            const int prow = mt * 32 + (r & 3) + 8 * (r >> 2) + 4 * half;
            if (prow < 100) {
                s_c2b[q][prow * 64 + lm]      = f2bf(acc0[r]);
                s_c2b[q][prow * 64 + 32 + lm] = f2bf(acc1[r]);
            }
        }
    }
    __syncthreads();

    // ---- Phase D: maxpool2 + bias + relu -> s_fb bf16 [5][5][64] ----
    for (int i = tq; i < 1600; i += 256) {
        const int co = i & 63, pp = i >> 6;
        const int py = pp / 5, px = pp % 5;
        const int p00 = (2 * py * 10 + 2 * px) * 64 + co;
        const float v0 = bf2f(s_c2b[q][p00]),       v1 = bf2f(s_c2b[q][p00 + 64]);
        const float v2 = bf2f(s_c2b[q][p00 + 640]), v3 = bf2f(s_c2b[q][p00 + 704]);
        const float m = fmaxf(fmaxf(v0, v1), fmaxf(v2, v3));
        s_fb[q][i] = f2bf(fmaxf(m + b2[co], 0.f));
    }
    __syncthreads();

    // ---- Phase E: gate logits ----
    {
        float gl[NE] = {0.f, 0.f, 0.f, 0.f, 0.f};
        for (int d = tq; d < 1600; d += 256) {
            const float fd = bf2f(s_fb[q][d]);
            #pragma unroll
            for (int e = 0; e < NE; e++) gl[e] = fmaf(fd, gw[d * NE + e], gl[e]);
        }
        #pragma unroll
        for (int e = 0; e < NE; e++) {
            #pragma unroll
            for (int off = 32; off; off >>= 1) gl[e] += __shfl_down(gl[e], off, 64);
        }
        if (lane == 0) {
            #pragma unroll
            for (int e = 0; e < NE; e++) s_red[q][w4 * NE + e] = gl[e];
        }
    }
    __syncthreads();
    if (tq == 0) {
        #pragma unroll
        for (int e = 0; e < NE; e++) {
            float s = gb[e];
            #pragma unroll
            for (int w_ = 0; w_ < 4; w_++) s += s_red[q][w_ * NE + e];
            s_gate[q][e] = s;
        }
    }
    __syncthreads();

    // ---- Phase F: softmax(5) + stable top-3 (uniform per thread) ----
    int   idxk[NK];
    float wk[NK];
    {
        float gv[NE], pe[NE];
        #pragma unroll
        for (int e = 0; e < NE; e++) gv[e] = s_gate[q][e];
        float mg = gv[0];
        #pragma unroll
        for (int e = 1; e < NE; e++) mg = fmaxf(mg, gv[e]);
        float se = 0.f;
        #pragma unroll
        for (int e = 0; e < NE; e++) { pe[e] = expf(gv[e] - mg); se += pe[e]; }
        const float inv = 1.f / se;
        #pragma unroll
        for (int e = 0; e < NE; e++) pe[e] *= inv;
        bool used[NE] = {false, false, false, false, false};
        #pragma unroll
        for (int k = 0; k < NK; k++) {
            int bi = 0; float bv = -1e30f;
            #pragma unroll
            for (int e = 0; e < NE; e++)
                if (!used[e] && pe[e] > bv) { bv = pe[e]; bi = e; }  // strict >: lowest idx ties
            used[bi] = true; idxk[k] = bi; wk[k] = bv;
        }
    }

    // ---- Phase G: top-3 expert GEMVs (float2-vectorized ew), weighted sum, softmax(10) ----
    {
        float a10[NC];
        #pragma unroll
        for (int h = 0; h < NC; h++) a10[h] = 0.f;
        for (int d = tq; d < 1600; d += 256) {
            const float fd = bf2f(s_fb[q][d]);
            #pragma unroll
            for (int k = 0; k < NK; k++) {
                const float2* ep2 = (const float2*)(ew + (idxk[k] * 1600 + d) * NC); // 8B-aligned
                const float wf = wk[k] * fd;
                const float2 u0 = ep2[0], u1 = ep2[1], u2 = ep2[2], u3 = ep2[3], u4 = ep2[4];
                a10[0] = fmaf(wf, u0.x, a10[0]); a10[1] = fmaf(wf, u0.y, a10[1]);
                a10[2] = fmaf(wf, u1.x, a10[2]); a10[3] = fmaf(wf, u1.y, a10[3]);
                a10[4] = fmaf(wf, u2.x, a10[4]); a10[5] = fmaf(wf, u2.y, a10[5]);
                a10[6] = fmaf(wf, u3.x, a10[6]); a10[7] = fmaf(wf, u3.y, a10[7]);
                a10[8] = fmaf(wf, u4.x, a10[8]); a10[9] = fmaf(wf, u4.y, a10[9]);
            }
        }
        #pragma unroll
        for (int h = 0; h < NC; h++) {
            #pragma unroll
            for (int off = 32; off; off >>= 1) a10[h] += __shfl_down(a10[h], off, 64);
        }
        if (lane == 0) {
            #pragma unroll
            for (int h = 0; h < NC; h++) s_red[q][w4 * NC + h] = a10[h];
        }
        __syncthreads();
        if (tq == 0) {
            float c10[NC];
            #pragma unroll
            for (int h = 0; h < NC; h++) {
                float s = 0.f;
                #pragma unroll
                for (int w_ = 0; w_ < 4; w_++) s += s_red[q][w_ * NC + h];
                c10[h] = s;
            }
            #pragma unroll
            for (int k = 0; k < NK; k++)
                #pragma unroll
                for (int h = 0; h < NC; h++)
                    c10[h] = fmaf(wk[k], eb[idxk[k] * NC + h], c10[h]);
            float mx = c10[0];
            #pragma unroll
            for (int h = 1; h < NC; h++) mx = fmaxf(mx, c10[h]);
            float se = 0.f;
            #pragma unroll
            for (int h = 0; h < NC; h++) { c10[h] = expf(c10[h] - mx); se += c10[h]; }
            const float inv = 1.f / se;
            #pragma unroll
            for (int h = 0; h < NC; h++) out[img * NC + h] = c10[h] * inv;
        }
    }
}

extern "C" void kernel_launch(void* const* d_in, const int* in_sizes, int n_in,
                              void* d_out, int out_size, void* d_ws, size_t ws_size,
                              hipStream_t stream) {
    const float* x   = (const float*)d_in[0];
    const float* w1  = (const float*)d_in[1];
    const float* b1  = (const float*)d_in[2];
    const float* w2  = (const float*)d_in[3];
    const float* b2  = (const float*)d_in[4];
    const float* gw  = (const float*)d_in[5];
    const float* gb  = (const float*)d_in[6];
    const float* ew  = (const float*)d_in[7];
    const float* eb  = (const float*)d_in[8];
    float* out = (float*)d_out;
    unsigned short* wsW = (unsigned short*)d_ws;   // 18944 bf16 = 37 KB

    prep_w<<<74, 256, 0, stream>>>(w2, w1, wsW);

    const int batch = in_sizes[0] / 784;   // 8192
    moe_fused<<<batch / 2, NT, 0, stream>>>(x, b1, wsW, b2, gw, gb, ew, eb, out);
}

// Round 15
// 206.463 us; speedup vs baseline: 5.2151x; 1.3338x over previous
//
#include <hip/hip_runtime.h>
#include <math.h>

#define NE 5
#define NK 3
#define NC 10
#define NT 512   // 8 waves = 2 image-quads of 4 waves

typedef __attribute__((ext_vector_type(8)))  short s16x8;   // 8 bf16 MFMA A/B frag
typedef __attribute__((ext_vector_type(16))) float f32x16;  // 32x32 MFMA C/D frag

__device__ __forceinline__ unsigned short f2bf(float f) {   // RNE float->bf16
    union { float f; unsigned u; } v; v.f = f;
    unsigned r = v.u + 0x7FFFu + ((v.u >> 16) & 1u);
    return (unsigned short)(r >> 16);
}
__device__ __forceinline__ float bf2f(unsigned short s) {
    union { unsigned u; float f; } v; v.u = ((unsigned)s) << 16;
    return v.f;
}

// ---- Prep kernel: weights -> bf16 MFMA B-fragments in d_ws.
// [0,18432): W2 frags [kk][nt][h][lane][8] (as R11-R13).
// [18432,18944): W1 frag (K=9 padded to 16).
// [19456,121856): W_all frags [s<100][nt<2][lane][8]: fused tail GEMM B operand.
//   col = nt*32+(lane&31): cols 0..49 = expert_w[e=col/10][k][h=col%10],
//   cols 50..54 = gate_w[k][col-50], cols 55..63 = 0.  k = s*16+(lane>>5)*8+j.
__global__ void prep_w(const float* __restrict__ w2, const float* __restrict__ w1,
                       const float* __restrict__ gw, const float* __restrict__ ew,
                       unsigned short* __restrict__ wsW) {
    const int idx = blockIdx.x * 256 + threadIdx.x;
    if (idx < 18432) {
        const int j    = idx & 7;
        const int lane = (idx >> 3) & 63;
        const int h    = (idx >> 9) & 1;
        const int nt   = (idx >> 10) & 1;
        const int kk   = idx >> 11;
        const int ci   = h * 16 + ((lane >> 5) << 3) + j;
        const int co   = nt * 32 + (lane & 31);
        wsW[idx] = f2bf(w2[(kk * 32 + ci) * 64 + co]);
    } else if (idx < 18944) {
        const int i2   = idx - 18432;
        const int j    = i2 & 7;
        const int lane = i2 >> 3;
        const int k    = ((lane >> 5) << 3) + j;
        const int co   = lane & 31;
        wsW[idx] = (k < 9) ? f2bf(w1[k * 32 + co]) : (unsigned short)0;
    } else if (idx >= 19456 && idx < 121856) {
        const int i3   = idx - 19456;
        const int j    = i3 & 7;
        const int lane = (i3 >> 3) & 63;
        const int nt   = (i3 >> 9) & 1;
        const int s    = i3 >> 10;
        const int k    = s * 16 + ((lane >> 5) << 3) + j;
        const int col  = nt * 32 + (lane & 31);
        float v = 0.f;
        if (col < 50)       v = ew[((col / 10) * 1600 + k) * 10 + (col % 10)];
        else if (col < 55)  v = gw[k * 5 + (col - 50)];
        wsW[idx] = f2bf(v);
    }
}

// TWO images per 512-thread block (wave-quad per image). Phases:
// A stage img bf16 -> c2b region; B conv1 MFMA + reg-maxpool -> p1b; C conv2 MFMA
// -> c2b; D pool+bias+relu -> fb; E' tail GEMM f@W_all via MFMA (quad's 4 waves
// split K=1600 into 4x400; A-frag = broadcast ds_read of fb, all C rows identical
// so only reg0/half0 matters; partials -> dead c2b region); reduce; serial top3+
// softmax tail on 1 thread/image. R13 post-mortem: E/F/G were 4 barriers + ~125
// L2 loads/thread dependent chain + 448KB L2 per block; now 50 MFMAs/wave + 200KB.
// LDS 51968B -> 3 blocks/CU.
__attribute__((amdgpu_flat_work_group_size(NT, NT)))
__global__ void moe_fused(const float* __restrict__ x,
                          const float* __restrict__ b1,
                          const unsigned short* __restrict__ wsW, const float* __restrict__ b2,
                          const float* __restrict__ gb, const float* __restrict__ eb,
                          float* __restrict__ out)
{
    __shared__ __align__(16) unsigned short s_p1b[2][156 * 32]; // pooled conv1, swizzled
    __shared__ __align__(16) unsigned short s_c2b[2][6400];     // img (A,B) / conv2 out (C,D) / tail partials (E')
    __shared__ __align__(16) unsigned short s_fb[2][1600];      // f bf16, flatten order

    const int t    = threadIdx.x;
    const int lane = t & 63;
    const int wv   = t >> 6;        // 0..7
    const int q    = wv >> 2;       // image slot
    const int w4   = wv & 3;        // wave within quad
    const int tq   = t & 255;       // thread within quad
    const int img  = blockIdx.x * 2 + q;

    // ---- Phase A: stage image as bf16 into c2b region ----
    {
        const float4* xq = (const float4*)(x + img * 784);
        ushort4* dst = (ushort4*)s_c2b[q];
        for (int i = tq; i < 196; i += 256) {
            float4 v = xq[i];
            ushort4 o; o.x = f2bf(v.x); o.y = f2bf(v.y); o.z = f2bf(v.z); o.w = f2bf(v.w);
            dst[i] = o;
        }
    }
    __syncthreads();

    // ---- Phase B: conv1 via MFMA + in-register maxpool -> s_p1b ----
    {
        const int cx   = lane & 31;
        const int half = lane >> 5;
        const int co   = lane & 31;
        const unsigned short* simg = s_c2b[q];
        s16x8 bw1 = *(const s16x8*)&wsW[18432 + lane * 8];
        const float b1co = b1[co];

        for (int pr = w4; pr < 12; pr += 4) {
            s16x8 afA = {0,0,0,0,0,0,0,0}, afB = {0,0,0,0,0,0,0,0};
            if (half == 0) {
                #pragma unroll
                for (int j = 0; j < 8; j++) {
                    const int ky = j / 3, kx = j % 3;
                    afA[j] = (short)simg[(2 * pr +     ky) * 28 + cx + kx];
                    afB[j] = (short)simg[(2 * pr + 1 + ky) * 28 + cx + kx];
                }
            } else {                                    // k=8 (ky=2,kx=2)
                afA[0] = (short)simg[(2 * pr + 2) * 28 + cx + 2];
                afB[0] = (short)simg[(2 * pr + 3) * 28 + cx + 2];
            }
            f32x16 accA, accB;
            #pragma unroll
            for (int i = 0; i < 16; i++) { accA[i] = 0.f; accB[i] = 0.f; }
            accA = __builtin_amdgcn_mfma_f32_32x32x16_bf16(afA, bw1, accA, 0, 0, 0);
            accB = __builtin_amdgcn_mfma_f32_32x32x16_bf16(afB, bw1, accB, 0, 0, 0);

            #pragma unroll
            for (int reg = 0; reg < 16; reg += 2) {
                const int row = (reg & 3) + 8 * (reg >> 2) + 4 * half;   // even
                if (row < 26) {
                    const int px  = row >> 1;
                    const int pos = pr * 13 + px;
                    float m = fmaxf(fmaxf(accA[reg], accA[reg + 1]),
                                    fmaxf(accB[reg], accB[reg + 1]));
                    m = fmaxf(m + b1co, 0.f);
                    const int slot = (co >> 3) ^ ((pos >> 1) & 3);
                    s_p1b[q][pos * 32 + slot * 8 + (co & 7)] = f2bf(m);
                }
            }
        }
    }
    __syncthreads();

    // ---- Phase C: conv2 via MFMA (wave w4 = M-tile, nt inner, 2 accs) ----
    {
        const int mt = w4;
        const int half = lane >> 5, lm = lane & 31;
        const int p = mt * 32 + lm;
        const int arow0 = (p < 100) ? ((p / 10) * 13 + (p % 10)) : 0;

        f32x16 acc0, acc1;
        #pragma unroll
        for (int i = 0; i < 16; i++) { acc0[i] = 0.f; acc1[i] = 0.f; }

        #pragma unroll
        for (int ky = 0; ky < 3; ky++)
        #pragma unroll
        for (int kx = 0; kx < 3; kx++) {
            const int kk = ky * 3 + kx;
            const int ar = arow0 + ky * 13 + kx;
            const int aswz = (ar >> 1) & 3;
            #pragma unroll
            for (int h = 0; h < 2; h++) {
                const int sp = 2 * h + half;
                s16x8 av  = *(const s16x8*)&s_p1b[q][ar * 32 + ((sp ^ aswz) << 3)];
                s16x8 bv0 = *(const s16x8*)&wsW[(((kk * 2 + 0) * 2 + h) * 64 + lane) * 8];
                s16x8 bv1 = *(const s16x8*)&wsW[(((kk * 2 + 1) * 2 + h) * 64 + lane) * 8];
                acc0 = __builtin_amdgcn_mfma_f32_32x32x16_bf16(av, bv0, acc0, 0, 0, 0);
                acc1 = __builtin_amdgcn_mfma_f32_32x32x16_bf16(av, bv1, acc1, 0, 0, 0);
            }
        }
        #pragma unroll
        for (int r = 0; r < 16; r++) {
            const int prow = mt * 32 + (r & 3) + 8 * (r >> 2) + 4 * half;
            if (prow < 100) {
                s_c2b[q][prow * 64 + lm]      = f2bf(acc0[r]);
                s_c2b[q][prow * 64 + 32 + lm] = f2bf(acc1[r]);
            }
        }
    }
    __syncthreads();

    // ---- Phase D: maxpool2 + bias + relu -> s_fb bf16 [5][5][64] ----
    for (int i = tq; i < 1600; i += 256) {
        const int co = i & 63, pp = i >> 6;
        const int py = pp / 5, px = pp % 5;
        const int p00 = (2 * py * 10 + 2 * px) * 64 + co;
        const float v0 = bf2f(s_c2b[q][p00]),       v1 = bf2f(s_c2b[q][p00 + 64]);
        const float v2 = bf2f(s_c2b[q][p00 + 640]), v3 = bf2f(s_c2b[q][p00 + 704]);
        const float m = fmaxf(fmaxf(v0, v1), fmaxf(v2, v3));
        s_fb[q][i] = f2bf(fmaxf(m + b2[co], 0.f));
    }
    __syncthreads();

    // ---- Phase E': tail GEMM f @ W_all via MFMA; quad's 4 waves split K=1600 ----
    {
        const unsigned short* wall = wsW + 19456;
        f32x16 acc0, acc1;
        #pragma unroll
        for (int i = 0; i < 16; i++) { acc0[i] = 0.f; acc1[i] = 0.f; }
        const int half = lane >> 5;
        #pragma unroll 1
        for (int i = 0; i < 25; i++) {
            const int s = w4 * 25 + i;
            s16x8 av  = *(const s16x8*)&s_fb[q][s * 16 + half * 8];     // broadcast read
            s16x8 bv0 = *(const s16x8*)&wall[((s * 2 + 0) * 64 + lane) * 8];
            s16x8 bv1 = *(const s16x8*)&wall[((s * 2 + 1) * 64 + lane) * 8];
            acc0 = __builtin_amdgcn_mfma_f32_32x32x16_bf16(av, bv0, acc0, 0, 0, 0);
            acc1 = __builtin_amdgcn_mfma_f32_32x32x16_bf16(av, bv1, acc1, 0, 0, 0);
        }
        // all C rows identical; row0 = reg0/half0 -> lanes 0..31 hold cols lane / lane+32
        float* pc = (float*)s_c2b[q];     // c2b dead after Phase D reads; 4x64 f32
        if (lane < 32) {
            pc[w4 * 64 + lane]      = acc0[0];
            pc[w4 * 64 + 32 + lane] = acc1[0];
        }
    }
    __syncthreads();

    // ---- reduce 4 partials (wave 0 of quad) ----
    {
        float* pc = (float*)s_c2b[q];
        if (w4 == 0) {
            float v = pc[lane] + pc[64 + lane] + pc[128 + lane] + pc[192 + lane];
            pc[lane] = v;
        }
    }
    __syncthreads();

    // ---- serial tail: gate softmax + stable top-3 + combine + softmax(10) ----
    if (tq == 0) {
        const float* pc = (const float*)s_c2b[q];
        float gv[NE], pe[NE];
        #pragma unroll
        for (int e = 0; e < NE; e++) gv[e] = pc[50 + e] + gb[e];
        float mg = gv[0];
        #pragma unroll
        for (int e = 1; e < NE; e++) mg = fmaxf(mg, gv[e]);
        float se = 0.f;
        #pragma unroll
        for (int e = 0; e < NE; e++) { pe[e] = expf(gv[e] - mg); se += pe[e]; }
        const float inv = 1.f / se;
        #pragma unroll
        for (int e = 0; e < NE; e++) pe[e] *= inv;

        int idxk[NK]; float wk[NK];
        bool used[NE] = {false, false, false, false, false};
        #pragma unroll
        for (int k = 0; k < NK; k++) {
            int bi = 0; float bv = -1e30f;
            #pragma unroll
            for (int e = 0; e < NE; e++)
                if (!used[e] && pe[e] > bv) { bv = pe[e]; bi = e; }  // strict >: lowest idx ties
            used[bi] = true; idxk[k] = bi; wk[k] = bv;
        }

        float c10[NC];
        #pragma unroll
        for (int h = 0; h < NC; h++) c10[h] = 0.f;
        #pragma unroll
        for (int k = 0; k < NK; k++) {
            const float* ebk = eb + idxk[k] * NC;
            const float* ek  = pc + idxk[k] * NC;
            #pragma unroll
            for (int h = 0; h < NC; h++)
                c10[h] = fmaf(wk[k], ek[h] + ebk[h], c10[h]);
        }
        float mx = c10[0];
        #pragma unroll
        for (int h = 1; h < NC; h++) mx = fmaxf(mx, c10[h]);
        float s2 = 0.f;
        #pragma unroll
        for (int h = 0; h < NC; h++) { c10[h] = expf(c10[h] - mx); s2 += c10[h]; }
        const float i2 = 1.f / s2;
        #pragma unroll
        for (int h = 0; h < NC; h++) out[img * NC + h] = c10[h] * i2;
    }
}

extern "C" void kernel_launch(void* const* d_in, const int* in_sizes, int n_in,
                              void* d_out, int out_size, void* d_ws, size_t ws_size,
                              hipStream_t stream) {
    const float* x   = (const float*)d_in[0];
    const float* w1  = (const float*)d_in[1];
    const float* b1  = (const float*)d_in[2];
    const float* w2  = (const float*)d_in[3];
    const float* b2  = (const float*)d_in[4];
    const float* gw  = (const float*)d_in[5];
    const float* gb  = (const float*)d_in[6];
    const float* ew  = (const float*)d_in[7];
    const float* eb  = (const float*)d_in[8];
    float* out = (float*)d_out;
    unsigned short* wsW = (unsigned short*)d_ws;   // 121856 bf16 ~= 238 KB

    prep_w<<<476, 256, 0, stream>>>(w2, w1, gw, ew, wsW);

    const int batch = in_sizes[0] / 784;   // 8192
    moe_fused<<<batch / 2, NT, 0, stream>>>(x, b1, wsW, b2, gb, eb, out);
}